// Round 12
// baseline (1350.734 us; speedup 1.0000x reference)
//
#include <hip/hip_runtime.h>
#include <hip/hip_bf16.h>
#include <cmath>

#define DEV_INLINE __device__ __forceinline__

constexpr int Bn = 128;
constexpr int Nn = 128;
constexpr int Fn = 13;
constexpr int Dn = 256;
constexpr int Ln = 8;
constexpr int Kn = 10;
constexpr int FFn = 512;
constexpr int Tn = Bn * Nn;   // 16384
constexpr int Rn = Tn * Kn;   // 163840

typedef __attribute__((ext_vector_type(4))) float f32x4;
typedef __attribute__((ext_vector_type(8))) short bf16x8;
typedef unsigned short us;

// ---------------- static device workspace ----------------
__device__ float g_x[Tn * Dn];
__device__ float g_skip[Tn * Dn];
__device__ float g_big[Tn * Dn];
__device__ float g_dm[Tn * Nn];
__device__ float g_u[Bn * FFn];
__device__ float g_r[Tn];
__device__ float g_pqbias[2048];
__device__ int   g_idx[Rn];
__device__ us g_bigb[Tn * 768];
__device__ us g_xb[Tn * Dn];
__device__ us g_attb[Tn * Dn];
__device__ us g_lf1b[Tn * Dn];
__device__ us g_pq[Tn * 1024];
__device__ us g_h2b[Rn * Dn];
__device__ us g_feat16[Tn * 32];
constexpr int OFF_ENC1 = 0;
constexpr int OFF_ENC2 = OFF_ENC1 + 512 * 32;
constexpr int OFF_W2A  = OFF_ENC2 + 256 * 512;
constexpr int OFF_W2B  = OFF_W2A + 256 * 512;
constexpr int OFF_PQ1  = OFF_W2B + 256 * 512;
constexpr int OFF_PQ2  = OFF_PQ1 + 1024 * 32;
constexpr int OFF_QKV  = OFF_PQ2 + 1024 * 256;
constexpr int OFF_OUT  = OFF_QKV + 8 * 768 * 256;
constexpr int OFF_FF1  = OFF_OUT + 8 * 256 * 256;
constexpr int OFF_FF2  = OFF_FF1 + 8 * 512 * 256;
constexpr int WT_TOTAL = OFF_FF2 + 8 * 256 * 512;
__device__ us g_wt[WT_TOTAL];

// fast gelu: 0.5x(1+tanh(u)) == x / (1 + exp(-2u))
DEV_INLINE float gelu_f(float x) {
    float x2 = x * x;
    float m = x * fmaf(x2, -0.07135537f, -1.59576912f); // -2u
    float t = __expf(m);
    return x * __builtin_amdgcn_rcpf(1.f + t);
}
DEV_INLINE us f2b(float x) {
    __hip_bfloat16 h = __float2bfloat16(x);
    return *(us*)&h;
}
DEV_INLINE float blo(unsigned u) { return __uint_as_float(u << 16); }
DEV_INLINE float bhi(unsigned u) { return __uint_as_float(u & 0xFFFF0000u); }
DEV_INLINE unsigned pk2(float a, float b) {
    float2 f; f.x = a; f.y = b;
    __hip_bfloat162 h = __float22bfloat162_rn(f);
    return *(unsigned*)&h;
}

#define GLOAD16(gp, lp)                                                            \
    __builtin_amdgcn_global_load_lds(                                              \
        (const __attribute__((address_space(1))) unsigned int*)(gp),               \
        (__attribute__((address_space(3))) unsigned int*)(lp), 16, 0, 0)

// =================== über-prep (8x-batched tiles) ===================
constexpr int U0 = 0;
constexpr int U1 = U0 + 2;
constexpr int U2 = U1 + 16;
constexpr int U3 = U2 + 16;
constexpr int U4 = U3 + 16;
constexpr int U5 = U4 + 192;
constexpr int U6 = U5 + 64;
constexpr int U7 = U6 + 128;
constexpr int U8 = U7 + 128;
constexpr int U9 = U8 + 128;
constexpr int U10 = U9 + 128;
constexpr int U11 = U10 + 256;
constexpr int U12 = U11 + 128;
constexpr int UPN = U12 + 128;

DEV_INLINE void prep_seg(const float* __restrict__ src, us* __restrict__ dst,
                         int Kreal, int Kpad, int Nd, long sstride, long dstride,
                         int gx, int gy, int lb, int tid, float* tile) {
    int z = lb / (gx * gy);
    int rem = lb - z * gx * gy;
    int by = rem / gx, bx = rem - by * gx;
    const float* s = src + (size_t)z * sstride;
    us* d = dst + (size_t)z * dstride;
    int cn = tid & 31, rk = tid >> 5;
    int kbase = by * 32, nbase = bx * 32;
#pragma unroll
    for (int p = 0; p < 4; p++) {
        int k = kbase + p * 8 + rk;
        float v = (k < Kreal) ? s[(size_t)k * Nd + nbase + cn] : 0.f;
        tile[(p * 8 + rk) * 33 + cn] = v;
    }
    __syncthreads();
#pragma unroll
    for (int p = 0; p < 4; p++) {
        int nl = p * 8 + rk;
        d[(size_t)(nbase + nl) * Kpad + kbase + cn] = f2b(tile[cn * 33 + nl]);
    }
    __syncthreads();
}

DEV_INLINE void prepPQ_seg(const float* __restrict__ w1, const float* __restrict__ b1,
                           us* __restrict__ dst, float* __restrict__ bdst,
                           int Kreal, int Kpad, int n, int tid) {
    for (int k = tid; k < Kpad; k += 256) {
        float v;
        if (n < 512) v = (k < Kreal) ? w1[(size_t)k * 512 + n] : 0.f;
        else {
            int m = n - 512;
            v = (k < Kreal) ? (w1[(size_t)(Kreal + k) * 512 + m] - w1[(size_t)k * 512 + m]) : 0.f;
        }
        dst[(size_t)n * Kpad + k] = f2b(v);
    }
    if (tid == 0) bdst[n] = (n < 512) ? 0.f : b1[n - 512];
}

__global__ __launch_bounds__(256) void k_uprep(
    const float* __restrict__ enc_w1, const float* __restrict__ enc_w2,
    const float* __restrict__ l1w2, const float* __restrict__ l2w2,
    const float* __restrict__ qkv_w, const float* __restrict__ out_w,
    const float* __restrict__ ff1w, const float* __restrict__ ff2w,
    const float* __restrict__ l1w1, const float* __restrict__ l1b1,
    const float* __restrict__ l2w1, const float* __restrict__ l2b1,
    const float* __restrict__ feat, const float* __restrict__ tin,
    const float* __restrict__ four_w1, const float* __restrict__ four_w2,
    const float* __restrict__ time_w, const float* __restrict__ pts,
    const float* __restrict__ mask,
    us* __restrict__ wt, float* __restrict__ pqbias, us* __restrict__ fp,
    float* __restrict__ u, int* __restrict__ idx) {
    __shared__ float shmem[1056];
    int b = blockIdx.x, tid = threadIdx.x;
    if (b < U1) {
#pragma unroll 1
        for (int i = 0; i < 8; i++)
            prep_seg(enc_w1, wt + OFF_ENC1, 13, 32, 512, 0, 0, 16, 1, (b - U0) * 8 + i, tid, shmem);
    } else if (b < U2) {
#pragma unroll 1
        for (int i = 0; i < 8; i++)
            prep_seg(enc_w2, wt + OFF_ENC2, 512, 512, 256, 0, 0, 8, 16, (b - U1) * 8 + i, tid, shmem);
    } else if (b < U3) {
#pragma unroll 1
        for (int i = 0; i < 8; i++)
            prep_seg(l1w2, wt + OFF_W2A, 512, 512, 256, 0, 0, 8, 16, (b - U2) * 8 + i, tid, shmem);
    } else if (b < U4) {
#pragma unroll 1
        for (int i = 0; i < 8; i++)
            prep_seg(l2w2, wt + OFF_W2B, 512, 512, 256, 0, 0, 8, 16, (b - U3) * 8 + i, tid, shmem);
    } else if (b < U5) {
#pragma unroll 1
        for (int i = 0; i < 8; i++)
            prep_seg(qkv_w, wt + OFF_QKV, 256, 256, 768, 256 * 768, 768 * 256, 24, 8, (b - U4) * 8 + i, tid, shmem);
    } else if (b < U6) {
#pragma unroll 1
        for (int i = 0; i < 8; i++)
            prep_seg(out_w, wt + OFF_OUT, 256, 256, 256, 256 * 256, 256 * 256, 8, 8, (b - U5) * 8 + i, tid, shmem);
    } else if (b < U7) {
#pragma unroll 1
        for (int i = 0; i < 8; i++)
            prep_seg(ff1w, wt + OFF_FF1, 256, 256, 512, 256 * 512, 512 * 256, 16, 8, (b - U6) * 8 + i, tid, shmem);
    } else if (b < U8) {
#pragma unroll 1
        for (int i = 0; i < 8; i++)
            prep_seg(ff2w, wt + OFF_FF2, 512, 512, 256, 512 * 256, 256 * 512, 8, 16, (b - U7) * 8 + i, tid, shmem);
    } else if (b < U9) {
#pragma unroll 1
        for (int i = 0; i < 8; i++)
            prepPQ_seg(l1w1, l1b1, wt + OFF_PQ1, pqbias, 13, 32, (b - U8) * 8 + i, tid);
    } else if (b < U10) {
#pragma unroll 1
        for (int i = 0; i < 8; i++)
            prepPQ_seg(l2w1, l2b1, wt + OFF_PQ2, pqbias + 1024, 256, 256, (b - U9) * 8 + i, tid);
    } else if (b < U11) {
#pragma unroll 1
        for (int i = 0; i < 8; i++) {
            int gid = ((b - U10) * 8 + i) * 256 + tid;
            int t = gid >> 5, c = gid & 31;
            fp[gid] = (c < Fn) ? f2b(feat[(size_t)t * Fn + c]) : (us)0;
        }
    } else if (b < U12) {
        float* e = shmem; float* e1 = shmem + 256; float* t2 = shmem + 768;
        int bb = b - U11;
        float tv = tin[bb];
        if (tid < 128) {
            const float emb = 0.07252236513366287f;
            float fr = expf(-emb * (float)tid);
            float ang = tv * fr * 1000.f;
            e[tid] = sinf(ang);
            e[tid + 128] = cosf(ang);
        }
        __syncthreads();
        for (int j = tid; j < 512; j += 256) {
            float s = 0.f;
            for (int i = 0; i < 256; i++) s += e[i] * four_w1[(size_t)i * 512 + j];
            e1[j] = s / (1.f + expf(-s));
        }
        __syncthreads();
        {
            float s = 0.f;
            for (int i = 0; i < 512; i++) s += e1[i] * four_w2[(size_t)i * 256 + tid];
            t2[tid] = s / (1.f + expf(-s));
        }
        __syncthreads();
        for (int j = tid; j < 512; j += 256) {
            float s = 0.f;
            for (int i = 0; i < 256; i++) s += t2[i] * time_w[(size_t)i * 512 + j];
            u[(size_t)bb * 512 + j] = s;
        }
    } else {
        float* px = shmem; float* py = shmem + 128; float* rr = shmem + 256;
        int bb = b - U12;
        if (tid < 128) {
            int n = tid;
            float shift = 999.f * (1.f - mask[bb * Nn + n]);
            float x = pts[(size_t)(bb * Nn + n) * 2 + 0] + shift;
            float y = pts[(size_t)(bb * Nn + n) * 2 + 1] + shift;
            px[n] = x; py[n] = y; rr[n] = x * x + y * y;
        }
        __syncthreads();
        if (tid < 128) {
            int n = tid;
            float x = px[n], y = py[n], rn = rr[n];
            float bd[Kn + 1]; int bi[Kn + 1];
#pragma unroll
            for (int j = 0; j <= Kn; j++) { bd[j] = 3.4e38f; bi[j] = -1; }
            for (int m = 0; m < Nn; m++) {
                float d = rn - 2.f * (x * px[m] + y * py[m]) + rr[m];
                if (d < bd[Kn]) {
                    int j = Kn;
                    while (j > 0 && d < bd[j - 1]) { bd[j] = bd[j - 1]; bi[j] = bi[j - 1]; j--; }
                    bd[j] = d; bi[j] = m;
                }
            }
            for (int j = 1; j <= Kn; j++) idx[(size_t)(bb * Nn + n) * Kn + j - 1] = bi[j];
        }
    }
}

// ---------------- MFMA GEMM: C = epi(A @ Bt^T + bias), 128x128 tile, XOR bank swizzle ----------------
template <int EPI, bool OBF>
__global__ __launch_bounds__(256) void k_mg2(const us* __restrict__ A,
                                             const us* __restrict__ Bt,
                                             const float* __restrict__ bias,
                                             void* __restrict__ Cp,
                                             int Kd, int Nd) {
    __shared__ __align__(16) us As[128 * 32];
    __shared__ __align__(16) us Bs[128 * 32];
    int tid = threadIdx.x;
    int m0 = blockIdx.y << 7, n0 = blockIdx.x << 7;
    int wave = tid >> 6, lane = tid & 63;
    int wm = (wave & 1) << 6, wn = (wave >> 1) << 6;
    int lm = lane & 15, quad = lane >> 4;
    int r0 = (wave << 5) + (lane >> 2);
    int colu = (((lane & 3) ^ ((lane >> 2) & 3)) << 3);
    const us* pa0 = A + (size_t)(m0 + r0) * Kd + colu;
    const us* pa1 = A + (size_t)(m0 + r0 + 16) * Kd + colu;
    const us* pb0 = Bt + (size_t)(n0 + r0) * Kd + colu;
    const us* pb1 = Bt + (size_t)(n0 + r0 + 16) * Kd + colu;
    auto lAs = (__attribute__((address_space(3))) us*)As;
    auto lBs = (__attribute__((address_space(3))) us*)Bs;
    int lbase = wave << 10;
    int fcol = ((quad ^ (lm & 3)) << 3);
    f32x4 acc[4][4] = {};
    for (int k0 = 0; k0 < Kd; k0 += 32) {
        __syncthreads();
        GLOAD16(pa0 + k0, lAs + lbase);
        GLOAD16(pa1 + k0, lAs + lbase + 512);
        GLOAD16(pb0 + k0, lBs + lbase);
        GLOAD16(pb1 + k0, lBs + lbase + 512);
        __syncthreads();
        bf16x8 afr[4], bfr[4];
#pragma unroll
        for (int i = 0; i < 4; i++) {
            afr[i] = *(const bf16x8*)&As[(wm + i * 16 + lm) * 32 + fcol];
            bfr[i] = *(const bf16x8*)&Bs[(wn + i * 16 + lm) * 32 + fcol];
        }
#pragma unroll
        for (int mf = 0; mf < 4; mf++)
#pragma unroll
            for (int nf = 0; nf < 4; nf++)
                acc[mf][nf] = __builtin_amdgcn_mfma_f32_16x16x32_bf16(afr[mf], bfr[nf], acc[mf][nf], 0, 0, 0);
    }
    float bvs[4];
#pragma unroll
    for (int nf = 0; nf < 4; nf++) bvs[nf] = bias[n0 + wn + nf * 16 + lm];
#pragma unroll
    for (int mf = 0; mf < 4; mf++) {
#pragma unroll
        for (int r = 0; r < 4; r++) {
            size_t row = (size_t)(m0 + wm + mf * 16 + (quad << 2) + r);
#pragma unroll
            for (int nf = 0; nf < 4; nf++) {
                float v = acc[mf][nf][r] + bvs[nf];
                if (EPI == 1) v = gelu_f(v);
                size_t ci = row * Nd + n0 + wn + nf * 16 + lm;
                if constexpr (OBF) ((us*)Cp)[ci] = f2b(v);
                else ((float*)Cp)[ci] = v;
            }
        }
    }
}

// ---------------- fused qkv GEMM + attention: block per (b,h), 256 threads ----------------
__global__ __launch_bounds__(256) void k_qattn(const us* __restrict__ xb,
                                               const us* __restrict__ Bt,
                                               const float* __restrict__ bias,
                                               const float* __restrict__ mask,
                                               us* __restrict__ attb) {
    __shared__ __align__(16) char smem[64512];
    us* Ps = (us*)smem;
    us* Qs = (us*)(smem + 34816);
    us* Ks = (us*)(smem + 45056);
    us* Vt = (us*)(smem + 55296);
    float* msk = (float*)(smem + 64000);
    us* As = (us*)smem;
    us* Bs = (us*)(smem + 8192);
    int bh = blockIdx.x;
    int b = bh >> 3, h = bh & 7;
    int tid = threadIdx.x;
    int wave = tid >> 6, lane = tid & 63;
    int lm = lane & 15, quad = lane >> 4;
    int wm = wave << 5;
    int colu = (((lane & 3) ^ ((lane >> 2) & 3)) << 3);
    int r0 = (wave << 5) + (lane >> 2);
    const us* pa0 = xb + (size_t)(b * 128 + r0) * 256 + colu;
    const us* pa1 = xb + (size_t)(b * 128 + r0 + 16) * 256 + colu;
    int seg0 = wave, seg1 = wave + 4;
    int n0_ = seg0 * 16 + (lane >> 2);
    int n1_ = seg1 * 16 + (lane >> 2);
    int g0 = (n0_ >> 5) * 256 + h * 32 + (n0_ & 31);
    int g1 = (n1_ >> 5) * 256 + h * 32 + (n1_ & 31);
    const us* pb0 = Bt + (size_t)g0 * 256 + colu;
    const us* pb1 = Bt + (size_t)g1 * 256 + colu;
    auto lAs = (__attribute__((address_space(3))) us*)As;
    auto lBs = (__attribute__((address_space(3))) us*)Bs;
    int fcol = ((quad ^ (lm & 3)) << 3);
    f32x4 gacc[2][6] = {};
    for (int k0 = 0; k0 < 256; k0 += 32) {
        __syncthreads();
        GLOAD16(pa0 + k0, lAs + (wave << 10));
        GLOAD16(pa1 + k0, lAs + (wave << 10) + 512);
        GLOAD16(pb0 + k0, lBs + (seg0 << 9));
        if (wave < 2) GLOAD16(pb1 + k0, lBs + (seg1 << 9));
        __syncthreads();
        bf16x8 afr[2], bfr[6];
#pragma unroll
        for (int mf = 0; mf < 2; mf++)
            afr[mf] = *(const bf16x8*)&As[(wm + mf * 16 + lm) * 32 + fcol];
#pragma unroll
        for (int nf = 0; nf < 6; nf++)
            bfr[nf] = *(const bf16x8*)&Bs[(nf * 16 + lm) * 32 + fcol];
#pragma unroll
        for (int mf = 0; mf < 2; mf++)
#pragma unroll
            for (int nf = 0; nf < 6; nf++)
                gacc[mf][nf] = __builtin_amdgcn_mfma_f32_16x16x32_bf16(afr[mf], bfr[nf], gacc[mf][nf], 0, 0, 0);
    }
    float bvq[6];
#pragma unroll
    for (int nf = 0; nf < 6; nf++) {
        int n = nf * 16 + lm;
        bvq[nf] = bias[(n >> 5) * 256 + h * 32 + (n & 31)];
    }
    __syncthreads();
#pragma unroll
    for (int mf = 0; mf < 2; mf++) {
#pragma unroll
        for (int r = 0; r < 4; r++) {
            int row = wm + mf * 16 + (quad << 2) + r;
#pragma unroll
            for (int nf = 0; nf < 6; nf++) {
                us hv = f2b(gacc[mf][nf][r] + bvq[nf]);
                int n = nf * 16 + lm;
                if (nf < 2) Qs[row * 40 + n] = hv;
                else if (nf < 4) Ks[row * 40 + (n - 32)] = hv;
                else Vt[(n - 64) * 136 + row] = hv;
            }
        }
    }
    if (tid < 128) msk[tid] = mask[b * 128 + tid];
    __syncthreads();
    f32x4 acc[2][8] = {};
    {
        bf16x8 aq[2];
#pragma unroll
        for (int mf = 0; mf < 2; mf++)
            aq[mf] = *(const bf16x8*)&Qs[(wm + mf * 16 + lm) * 40 + (quad << 3)];
#pragma unroll
        for (int nf = 0; nf < 8; nf++) {
            bf16x8 bk = *(const bf16x8*)&Ks[(nf * 16 + lm) * 40 + (quad << 3)];
            acc[0][nf] = __builtin_amdgcn_mfma_f32_16x16x32_bf16(aq[0], bk, acc[0][nf], 0, 0, 0);
            acc[1][nf] = __builtin_amdgcn_mfma_f32_16x16x32_bf16(aq[1], bk, acc[1][nf], 0, 0, 0);
        }
    }
    {
        const float sc = 0.17677669529663687f;
        float mkc[8];
#pragma unroll
        for (int nf = 0; nf < 8; nf++) mkc[nf] = msk[nf * 16 + lm];
#pragma unroll
        for (int mf = 0; mf < 2; mf++) {
#pragma unroll
            for (int nf = 0; nf < 8; nf++)
#pragma unroll
                for (int r = 0; r < 4; r++) {
                    float s = acc[mf][nf][r];
                    acc[mf][nf][r] = mkc[nf] > 0.f ? s * sc : -1.0e9f;
                }
#pragma unroll
            for (int r = 0; r < 4; r++) {
                float m = acc[mf][0][r];
#pragma unroll
                for (int nf = 1; nf < 8; nf++) m = fmaxf(m, acc[mf][nf][r]);
                m = fmaxf(m, __shfl_xor(m, 1, 64));
                m = fmaxf(m, __shfl_xor(m, 2, 64));
                m = fmaxf(m, __shfl_xor(m, 4, 64));
                m = fmaxf(m, __shfl_xor(m, 8, 64));
                float s = 0.f;
#pragma unroll
                for (int nf = 0; nf < 8; nf++) {
                    float p = __expf(acc[mf][nf][r] - m);
                    acc[mf][nf][r] = p;
                    s += p;
                }
                s += __shfl_xor(s, 1, 64);
                s += __shfl_xor(s, 2, 64);
                s += __shfl_xor(s, 4, 64);
                s += __shfl_xor(s, 8, 64);
                float linv = __builtin_amdgcn_rcpf(s);
                int prow = wm + mf * 16 + (quad << 2) + r;
#pragma unroll
                for (int nf = 0; nf < 8; nf++)
                    Ps[prow * 136 + nf * 16 + lm] = f2b(acc[mf][nf][r] * linv);
            }
        }
    }
    __syncthreads();
    f32x4 oacc[2][2] = {};
    for (int kt = 0; kt < 4; kt++) {
        bf16x8 ap[2], bv[2];
#pragma unroll
        for (int mf = 0; mf < 2; mf++)
            ap[mf] = *(const bf16x8*)&Ps[(wm + mf * 16 + lm) * 136 + kt * 32 + (quad << 3)];
#pragma unroll
        for (int nf = 0; nf < 2; nf++)
            bv[nf] = *(const bf16x8*)&Vt[(nf * 16 + lm) * 136 + kt * 32 + (quad << 3)];
#pragma unroll
        for (int mf = 0; mf < 2; mf++)
#pragma unroll
            for (int nf = 0; nf < 2; nf++)
                oacc[mf][nf] = __builtin_amdgcn_mfma_f32_16x16x32_bf16(ap[mf], bv[nf], oacc[mf][nf], 0, 0, 0);
    }
#pragma unroll
    for (int mf = 0; mf < 2; mf++)
#pragma unroll
        for (int r = 0; r < 4; r++) {
            int row = wm + mf * 16 + (quad << 2) + r;
#pragma unroll
            for (int nf = 0; nf < 2; nf++)
                attb[(size_t)(b * 128 + row) * 256 + h * 32 + nf * 16 + lm] = f2b(oacc[mf][nf][r]);
        }
}

// ---------------- fully-fused FFN sublayer: out-proj + LN1 + ff1 + ff2 + gamma*mask + LN2 ----------------
// 32-row tiles (512 blocks), 512 threads (8 waves; wave w owns N cols w*32..+32, full 32 M rows).
// LDS 64KB: xln [0,16K), h [16K,48K), Bs [48K,64K); As/part/stat overlaid in dead regions.
template <bool FINAL>
__global__ __launch_bounds__(512) void k_ffn(const us* __restrict__ A,      // attb
                                             const us* __restrict__ Wout,   // [256][256]
                                             const float* __restrict__ bout,
                                             const us* __restrict__ res,    // xb (layer input)
                                             const float* __restrict__ ln1gv,
                                             const float* __restrict__ ln1bv,
                                             const us* __restrict__ W1t,    // [512][256]
                                             const float* __restrict__ b1,
                                             const us* __restrict__ W2t,    // [256][512]
                                             const float* __restrict__ b2,
                                             const float* __restrict__ gamma,
                                             const float* __restrict__ mask,
                                             const float* __restrict__ ln2gv,
                                             const float* __restrict__ ln2bv,
                                             const float* __restrict__ skip,
                                             us* __restrict__ xbout,
                                             float* __restrict__ finout) {
    __shared__ __align__(16) char smem[65536];
    us* xln = (us*)smem;                       // 32*256 us, swizzled (32 blocks, ^row)
    us* hS  = (us*)(smem + 16384);             // 32*512 us, swizzled (64 blocks, ^row)
    us* Bs  = (us*)(smem + 49152);             // 256*32 us
    us* As  = (us*)(smem + 16384);             // p1 only (aliases hS, dead then)
    float2* part = (float2*)(smem + 18432);    // 8*32 (aliases hS; p1: h unused, p3-epi: h dead)
    float2* stat = (float2*)(smem + 20480);    // 32
    int tid = threadIdx.x;
    int m0 = blockIdx.x << 5;
    int wave = tid >> 6, lane = tid & 63;
    int wn = wave << 5;
    int lm = lane & 15, quad = lane >> 4;
    int colu = (((lane & 3) ^ ((lane >> 2) & 3)) << 3);
    int ar = (wave << 4) + (lane >> 2);   // waves 0-1 stage A rows 0..31
    int br = (wave << 5) + (lane >> 2);   // each wave stages its own 32 B rows
    auto lAs = (__attribute__((address_space(3))) us*)As;
    auto lBs = (__attribute__((address_space(3))) us*)Bs;
    int fcol = ((quad ^ (lm & 3)) << 3);
    // ===== phase 1: out-proj (K=256) =====
    {
        const us* pa = A + (size_t)(m0 + ar) * 256 + colu;
        const us* pb0 = Wout + (size_t)br * 256 + colu;
        const us* pb1 = Wout + (size_t)(br + 16) * 256 + colu;
        f32x4 acc[2][2] = {};
        for (int k0 = 0; k0 < 256; k0 += 32) {
            __syncthreads();
            if (wave < 2) GLOAD16(pa + k0, lAs + (wave << 9));
            GLOAD16(pb0 + k0, lBs + (wave << 10));
            GLOAD16(pb1 + k0, lBs + (wave << 10) + 512);
            __syncthreads();
            bf16x8 afr[2], bfr[2];
#pragma unroll
            for (int i = 0; i < 2; i++)
                afr[i] = *(const bf16x8*)&As[(i * 16 + lm) * 32 + fcol];
#pragma unroll
            for (int j = 0; j < 2; j++)
                bfr[j] = *(const bf16x8*)&Bs[(wn + j * 16 + lm) * 32 + fcol];
#pragma unroll
            for (int mf = 0; mf < 2; mf++)
#pragma unroll
                for (int nf = 0; nf < 2; nf++)
                    acc[mf][nf] = __builtin_amdgcn_mfma_f32_16x16x32_bf16(afr[mf], bfr[nf], acc[mf][nf], 0, 0, 0);
        }
        // LN1 epilogue
        float bvs[2];
#pragma unroll
        for (int nf = 0; nf < 2; nf++) bvs[nf] = bout[wn + nf * 16 + lm];
#pragma unroll
        for (int mf = 0; mf < 2; mf++) {
#pragma unroll
            for (int r = 0; r < 4; r++) {
                int rowl = mf * 16 + (quad << 2) + r;
                size_t row = (size_t)(m0 + rowl);
                float s1 = 0.f, s2 = 0.f;
#pragma unroll
                for (int nf = 0; nf < 2; nf++) {
                    int col = wn + nf * 16 + lm;
                    float rv = blo((unsigned)res[row * 256 + col]);
                    float v = rv + acc[mf][nf][r] + bvs[nf];
                    acc[mf][nf][r] = v;
                    s1 += v; s2 += v * v;
                }
                s1 += __shfl_xor(s1, 1, 64); s2 += __shfl_xor(s2, 1, 64);
                s1 += __shfl_xor(s1, 2, 64); s2 += __shfl_xor(s2, 2, 64);
                s1 += __shfl_xor(s1, 4, 64); s2 += __shfl_xor(s2, 4, 64);
                s1 += __shfl_xor(s1, 8, 64); s2 += __shfl_xor(s2, 8, 64);
                if (lm == 0) { float2 p; p.x = s1; p.y = s2; part[wave * 32 + rowl] = p; }
            }
        }
        __syncthreads();
        if (tid < 32) {
            float s = 0.f, q = 0.f;
#pragma unroll
            for (int w = 0; w < 8; w++) { float2 p = part[w * 32 + tid]; s += p.x; q += p.y; }
            float mean = s * (1.f / 256.f);
            float var = q * (1.f / 256.f) - mean * mean;
            float2 st; st.x = mean; st.y = rsqrtf(var + 1e-5f);
            stat[tid] = st;
        }
        __syncthreads();
        float gvs[2], bts[2];
#pragma unroll
        for (int nf = 0; nf < 2; nf++) {
            int col = wn + nf * 16 + lm;
            gvs[nf] = ln1gv[col];
            bts[nf] = ln1bv[col];
        }
#pragma unroll
        for (int mf = 0; mf < 2; mf++) {
#pragma unroll
            for (int r = 0; r < 4; r++) {
                int rowl = mf * 16 + (quad << 2) + r;
                float2 st = stat[rowl];
#pragma unroll
                for (int nf = 0; nf < 2; nf++) {
                    int col = wn + nf * 16 + lm;
                    float nv = fmaf((acc[mf][nf][r] - st.x) * st.y, gvs[nf], bts[nf]);
                    int phys = (col >> 3) ^ rowl;
                    xln[rowl * 256 + (phys << 3) + (col & 7)] = f2b(nv);
                }
            }
        }
        __syncthreads(); // xln complete; As/part/stat region (hS) free for reuse
    }
    // ===== phase 2: ff1 (K=256, N=512 in two halves) -> h LDS =====
#pragma unroll 1
    for (int nh = 0; nh < 2; nh++) {
        const us* Bt2 = W1t + (size_t)(nh * 256) * 256;
        const us* qb0 = Bt2 + (size_t)br * 256 + colu;
        const us* qb1 = Bt2 + (size_t)(br + 16) * 256 + colu;
        f32x4 acc2[2][2] = {};
        for (int k0 = 0; k0 < 256; k0 += 32) {
            __syncthreads();
            GLOAD16(qb0 + k0, lBs + (wave << 10));
            GLOAD16(qb1 + k0, lBs + (wave << 10) + 512);
            __syncthreads();
            bf16x8 afr[2], bfr[2];
#pragma unroll
            for (int i = 0; i < 2; i++) {
                int rowi = i * 16 + lm;
                int phys = ((k0 >> 3) + quad) ^ rowi;
                afr[i] = *(const bf16x8*)&xln[rowi * 256 + (phys << 3)];
            }
#pragma unroll
            for (int j = 0; j < 2; j++)
                bfr[j] = *(const bf16x8*)&Bs[(wn + j * 16 + lm) * 32 + fcol];
#pragma unroll
            for (int mf = 0; mf < 2; mf++)
#pragma unroll
                for (int nf = 0; nf < 2; nf++)
                    acc2[mf][nf] = __builtin_amdgcn_mfma_f32_16x16x32_bf16(afr[mf], bfr[nf], acc2[mf][nf], 0, 0, 0);
        }
        float b1v[2];
#pragma unroll
        for (int nf = 0; nf < 2; nf++) b1v[nf] = b1[nh * 256 + wn + nf * 16 + lm];
#pragma unroll
        for (int mf = 0; mf < 2; mf++) {
#pragma unroll
            for (int r = 0; r < 4; r++) {
                int rowl = mf * 16 + (quad << 2) + r;
#pragma unroll
                for (int nf = 0; nf < 2; nf++) {
                    int gcol = nh * 256 + wn + nf * 16 + lm;
                    float v = gelu_f(acc2[mf][nf][r] + b1v[nf]);
                    int phys = (gcol >> 3) ^ rowl;
                    hS[rowl * 512 + (phys << 3) + (gcol & 7)] = f2b(v);
                }
            }
        }
    }
    // ===== phase 3: ff2 (K=512) + gamma*mask + LN2 =====
    {
        const us* pc0 = W2t + (size_t)br * 512 + colu;
        const us* pc1 = W2t + (size_t)(br + 16) * 512 + colu;
        f32x4 acc3[2][2] = {};
        for (int k0 = 0; k0 < 512; k0 += 32) {
            __syncthreads();
            GLOAD16(pc0 + k0, lBs + (wave << 10));
            GLOAD16(pc1 + k0, lBs + (wave << 10) + 512);
            __syncthreads();
            bf16x8 afr[2], bfr[2];
#pragma unroll
            for (int i = 0; i < 2; i++) {
                int rowi = i * 16 + lm;
                int phys = ((k0 >> 3) + quad) ^ rowi;
                afr[i] = *(const bf16x8*)&hS[rowi * 512 + (phys << 3)];
            }
#pragma unroll
            for (int j = 0; j < 2; j++)
                bfr[j] = *(const bf16x8*)&Bs[(wn + j * 16 + lm) * 32 + fcol];
#pragma unroll
            for (int mf = 0; mf < 2; mf++)
#pragma unroll
                for (int nf = 0; nf < 2; nf++)
                    acc3[mf][nf] = __builtin_amdgcn_mfma_f32_16x16x32_bf16(afr[mf], bfr[nf], acc3[mf][nf], 0, 0, 0);
        }
        __syncthreads(); // all h reads done before part/stat reuse of hS region
        float b2v[2], gmv[2];
#pragma unroll
        for (int nf = 0; nf < 2; nf++) {
            int col = wn + nf * 16 + lm;
            b2v[nf] = b2[col];
            gmv[nf] = gamma[col];
        }
#pragma unroll
        for (int mf = 0; mf < 2; mf++) {
#pragma unroll
            for (int r = 0; r < 4; r++) {
                int rowl = mf * 16 + (quad << 2) + r;
                size_t row = (size_t)(m0 + rowl);
                float mrow = mask[row];
                float s1 = 0.f, s2 = 0.f;
#pragma unroll
                for (int nf = 0; nf < 2; nf++) {
                    int col = wn + nf * 16 + lm;
                    int phys = (col >> 3) ^ rowl;
                    float xv = blo((unsigned)xln[rowl * 256 + (phys << 3) + (col & 7)]);
                    float v = fmaf((acc3[mf][nf][r] + b2v[nf]) * gmv[nf], mrow, xv);
                    acc3[mf][nf][r] = v;
                    s1 += v; s2 += v * v;
                }
                s1 += __shfl_xor(s1, 1, 64); s2 += __shfl_xor(s2, 1, 64);
                s1 += __shfl_xor(s1, 2, 64); s2 += __shfl_xor(s2, 2, 64);
                s1 += __shfl_xor(s1, 4, 64); s2 += __shfl_xor(s2, 4, 64);
                s1 += __shfl_xor(s1, 8, 64); s2 += __shfl_xor(s2, 8, 64);
                if (lm == 0) { float2 p; p.x = s1; p.y = s2; part[wave * 32 + rowl] = p; }
            }
        }
        __syncthreads();
        if (tid < 32) {
            float s = 0.f, q = 0.f;
#pragma unroll
            for (int w = 0; w < 8; w++) { float2 p = part[w * 32 + tid]; s += p.x; q += p.y; }
            float mean = s * (1.f / 256.f);
            float var = q * (1.f / 256.f) - mean * mean;
            float2 st; st.x = mean; st.y = rsqrtf(var + 1e-5f);
            stat[tid] = st;
        }
        __syncthreads();
        float gvs[2], bts[2];
#pragma unroll
        for (int nf = 0; nf < 2; nf++) {
            int col = wn + nf * 16 + lm;
            gvs[nf] = ln2gv[col];
            bts[nf] = ln2bv[col];
        }
#pragma unroll
        for (int mf = 0; mf < 2; mf++) {
#pragma unroll
            for (int r = 0; r < 4; r++) {
                int rowl = mf * 16 + (quad << 2) + r;
                size_t row = (size_t)(m0 + rowl);
                float2 st = stat[rowl];
#pragma unroll
                for (int nf = 0; nf < 2; nf++) {
                    int col = wn + nf * 16 + lm;
                    float nv = fmaf((acc3[mf][nf][r] - st.x) * st.y, gvs[nf], bts[nf]);
                    if (FINAL) finout[row * 256 + col] = nv + skip[row * 256 + col];
                    else xbout[row * 256 + col] = f2b(nv);
                }
            }
        }
    }
}

// ---------------- fused KNN GEMM2, BK=64, XOR swizzle ----------------
__global__ __launch_bounds__(512) void k_knng(const us* __restrict__ pq,
                                              const int* __restrict__ idx,
                                              const us* __restrict__ Bt,
                                              const float* __restrict__ bias,
                                              us* __restrict__ h2b) {
    __shared__ __align__(16) us As[128 * 64];
    __shared__ __align__(16) us Bs[256 * 64];
    int tid = threadIdx.x;
    int m0 = blockIdx.x << 7;
    int wave = tid >> 6, lane = tid & 63;
    int wm = (wave & 1) << 6, wn = (wave >> 1) << 6;
    int lm = lane & 15, quad = lane >> 4;
    int arow = tid >> 2, acolu = (tid & 3) << 4;
    int asw = arow & 7;
    int ablk0 = ((tid & 3) << 1) ^ asw, ablk1 = (((tid & 3) << 1) + 1) ^ asw;
    int r = m0 + arow;
    int tok = r / 10;
    int nb = idx[r];
    int prow = (tok & ~127) + nb;
    const us* Pp = pq + (size_t)prow * 1024 + acolu;
    const us* Qp = pq + (size_t)tok * 1024 + 512 + acolu;
    int brow = (wave << 5) + (lane >> 3);
    int bcol = (((lane & 7) ^ (lane >> 3)) << 3);
    const us* pb = Bt + (size_t)brow * 512 + bcol;
    auto lBs = (__attribute__((address_space(3))) us*)Bs;
    int lbase = wave << 11;
    int fsw = lm & 7;
    f32x4 acc[4][4] = {};
    for (int k0 = 0; k0 < 512; k0 += 64) {
        uint4 pv0 = *(const uint4*)(Pp + k0);
        uint4 pv1 = *(const uint4*)(Pp + k0 + 8);
        uint4 qv0 = *(const uint4*)(Qp + k0);
        uint4 qv1 = *(const uint4*)(Qp + k0 + 8);
        uint4 h0, h1;
        h0.x = pk2(gelu_f(blo(pv0.x) + blo(qv0.x)), gelu_f(bhi(pv0.x) + bhi(qv0.x)));
        h0.y = pk2(gelu_f(blo(pv0.y) + blo(qv0.y)), gelu_f(bhi(pv0.y) + bhi(qv0.y)));
        h0.z = pk2(gelu_f(blo(pv0.z) + blo(qv0.z)), gelu_f(bhi(pv0.z) + bhi(qv0.z)));
        h0.w = pk2(gelu_f(blo(pv0.w) + blo(qv0.w)), gelu_f(bhi(pv0.w) + bhi(qv0.w)));
        h1.x = pk2(gelu_f(blo(pv1.x) + blo(qv1.x)), gelu_f(bhi(pv1.x) + bhi(qv1.x)));
        h1.y = pk2(gelu_f(blo(pv1.y) + blo(qv1.y)), gelu_f(bhi(pv1.y) + bhi(qv1.y)));
        h1.z = pk2(gelu_f(blo(pv1.z) + blo(qv1.z)), gelu_f(bhi(pv1.z) + bhi(qv1.z)));
        h1.w = pk2(gelu_f(blo(pv1.w) + blo(qv1.w)), gelu_f(bhi(pv1.w) + bhi(qv1.w)));
        __syncthreads();
        GLOAD16(pb + k0, lBs + lbase);
        GLOAD16(pb + k0 + 8 * 512, lBs + lbase + 512);
        GLOAD16(pb + k0 + 16 * 512, lBs + lbase + 1024);
        GLOAD16(pb + k0 + 24 * 512, lBs + lbase + 1536);
        *(uint4*)&As[arow * 64 + (ablk0 << 3)] = h0;
        *(uint4*)&As[arow * 64 + (ablk1 << 3)] = h1;
        __syncthreads();
#pragma unroll
        for (int sub = 0; sub < 2; sub++) {
            int lblk = (sub << 2) + quad;
            int fcol = ((lblk ^ fsw) << 3);
            bf16x8 afr[4], bfr[4];
#pragma unroll
            for (int i = 0; i < 4; i++) {
                afr[i] = *(const bf16x8*)&As[(wm + i * 16 + lm) * 64 + fcol];
                bfr[i] = *(const bf16x8*)&Bs[(wn + i * 16 + lm) * 64 + fcol];
            }
#pragma unroll
            for (int mf = 0; mf < 4; mf++)
#pragma unroll
                for (int nf = 0; nf < 4; nf++)
                    acc[mf][nf] = __builtin_amdgcn_mfma_f32_16x16x32_bf16(afr[mf], bfr[nf], acc[mf][nf], 0, 0, 0);
        }
    }
    float bvs[4];
#pragma unroll
    for (int nf = 0; nf < 4; nf++) bvs[nf] = bias[wn + nf * 16 + lm];
#pragma unroll
    for (int mf = 0; mf < 4; mf++) {
#pragma unroll
        for (int rr = 0; rr < 4; rr++) {
            size_t row = (size_t)(m0 + wm + mf * 16 + (quad << 2) + rr);
#pragma unroll
            for (int nf = 0; nf < 4; nf++) {
                float v = gelu_f(acc[mf][nf][rr] + bvs[nf]);
                h2b[row * 256 + wn + nf * 16 + lm] = f2b(v);
            }
        }
    }
}

// ---------------- pass-1 mean + shift + rownorm ----------------
__global__ __launch_bounds__(64) void k_mean1s(const us* __restrict__ h2b,
                                               const float* __restrict__ mask,
                                               us* __restrict__ lfb,
                                               float* __restrict__ big,
                                               float* __restrict__ r) {
    int t = blockIdx.x, lane = threadIdx.x;
    int c = lane << 2;
    const us* p = h2b + (size_t)t * Kn * 256 + c;
    float s0 = 0.f, s1 = 0.f, s2 = 0.f, s3 = 0.f;
#pragma unroll
    for (int k = 0; k < Kn; k++) {
        uint2 v = *(const uint2*)(p + k * 256);
        s0 += blo(v.x); s1 += bhi(v.x);
        s2 += blo(v.y); s3 += bhi(v.y);
    }
    s0 *= 0.1f; s1 *= 0.1f; s2 *= 0.1f; s3 *= 0.1f;
    uint2 ob; ob.x = pk2(s0, s1); ob.y = pk2(s2, s3);
    *(uint2*)&lfb[(size_t)t * 256 + c] = ob;
    float sh = 999.f * (1.f - mask[t]);
    float4 w; w.x = s0 + sh; w.y = s1 + sh; w.z = s2 + sh; w.w = s3 + sh;
    *(float4*)&big[(size_t)t * 256 + c] = w;
    float sq = w.x * w.x + w.y * w.y + w.z * w.z + w.w * w.w;
#pragma unroll
    for (int off = 32; off; off >>= 1) sq += __shfl_xor(sq, off, 64);
    if (lane == 0) r[t] = sq;
}

// ---------------- pairwise distances (f32, 64x64 tiles) ----------------
__global__ __launch_bounds__(256) void k_dist(const float* __restrict__ fe,
                                              const float* __restrict__ r,
                                              float* __restrict__ Dm) {
    int b = blockIdx.z;
    int m0 = blockIdx.x * 64, n0 = blockIdx.y * 64;
    const float* A = fe + (size_t)b * Nn * Dn;
    __shared__ float As[16][68];
    __shared__ float Bs[16][68];
    int tid = threadIdx.x;
    int tx = tid & 15, ty = tid >> 4;
    int ar = tid >> 2, ac = (tid & 3) << 2;
    float acc[4][4] = {};
    for (int k0 = 0; k0 < Dn; k0 += 16) {
        float4 av = *(const float4*)&A[(size_t)(n0 + ar) * Dn + k0 + ac];
        float4 bv = *(const float4*)&A[(size_t)(m0 + ar) * Dn + k0 + ac];
        __syncthreads();
        As[ac + 0][ar] = av.x; As[ac + 1][ar] = av.y; As[ac + 2][ar] = av.z; As[ac + 3][ar] = av.w;
        Bs[ac + 0][ar] = bv.x; Bs[ac + 1][ar] = bv.y; Bs[ac + 2][ar] = bv.z; Bs[ac + 3][ar] = bv.w;
        __syncthreads();
#pragma unroll
        for (int kk = 0; kk < 16; kk++) {
            float4 a = *(const float4*)&As[kk][ty << 2];
            float4 b2 = *(const float4*)&Bs[kk][tx << 2];
            acc[0][0] += a.x * b2.x; acc[0][1] += a.x * b2.y; acc[0][2] += a.x * b2.z; acc[0][3] += a.x * b2.w;
            acc[1][0] += a.y * b2.x; acc[1][1] += a.y * b2.y; acc[1][2] += a.y * b2.z; acc[1][3] += a.y * b2.w;
            acc[2][0] += a.z * b2.x; acc[2][1] += a.z * b2.y; acc[2][2] += a.z * b2.z; acc[2][3] += a.z * b2.w;
            acc[3][0] += a.w * b2.x; acc[3][1] += a.w * b2.y; acc[3][2] += a.w * b2.z; acc[3][3] += a.w * b2.w;
        }
    }
    float4 rm = *(const float4*)&r[b * Nn + m0 + (tx << 2)];
#pragma unroll
    for (int i = 0; i < 4; i++) {
        int n = n0 + (ty << 2) + i;
        float rn = r[b * Nn + n];
        float4 v;
        v.x = rn - 2.f * acc[i][0] + rm.x;
        v.y = rn - 2.f * acc[i][1] + rm.y;
        v.z = rn - 2.f * acc[i][2] + rm.z;
        v.w = rn - 2.f * acc[i][3] + rm.w;
        *(float4*)&Dm[(size_t)b * Nn * Nn + (size_t)n * Nn + m0 + (tx << 2)] = v;
    }
}

__global__ __launch_bounds__(128) void k_topkg(const float* __restrict__ Dm, int* __restrict__ idx) {
    int b = blockIdx.x, n = threadIdx.x;
    const float* row = Dm + (size_t)b * Nn * Nn + (size_t)n * Nn;
    float bd[Kn + 1]; int bi[Kn + 1];
#pragma unroll
    for (int j = 0; j <= Kn; j++) { bd[j] = 3.4e38f; bi[j] = -1; }
    for (int m = 0; m < Nn; m++) {
        float d = row[m];
        if (d < bd[Kn]) {
            int j = Kn;
            while (j > 0 && d < bd[j - 1]) { bd[j] = bd[j - 1]; bi[j] = bi[j - 1]; j--; }
            bd[j] = d; bi[j] = m;
        }
    }
    for (int j = 1; j <= Kn; j++) idx[(size_t)(b * Nn + n) * Kn + j - 1] = bi[j];
}

// ---------------- pass-2 mean fused with combine (bf16 residual out) ----------------
__global__ __launch_bounds__(256) void k_meanc(const us* __restrict__ h2b,
                                               const float* __restrict__ u,
                                               const float* __restrict__ mask,
                                               const float* __restrict__ x,
                                               float* __restrict__ skip,
                                               us* __restrict__ xb) {
    int t = blockIdx.x, c = threadIdx.x;
    const us* p = h2b + (size_t)t * Kn * 256 + c;
    float s = 0.f;
#pragma unroll
    for (int k = 0; k < Kn; k++) s += blo((unsigned)p[k * 256]);
    s *= 0.1f;
    int b = t >> 7;
    float m = mask[t];
    float xv = x[(size_t)t * Dn + c];
    float sc = u[(size_t)b * 512 + c];
    float sh = u[(size_t)b * 512 + 256 + c];
    float v = xv * (1.f + m * sc) + m * sh + s;
    skip[(size_t)t * Dn + c] = v;
    xb[(size_t)t * Dn + c] = f2b(v);
}

extern "C" void kernel_launch(void* const* d_in, const int* in_sizes, int n_in,
                              void* d_out, int out_size, void* d_ws, size_t ws_size,
                              hipStream_t stream) {
    (void)in_sizes; (void)n_in; (void)out_size; (void)d_ws; (void)ws_size;
    const float* f_feat = (const float*)d_in[0];
    const float* f_pts  = (const float*)d_in[1];
    const float* f_mask = (const float*)d_in[2];
    const float* f_time = (const float*)d_in[3];
    const float* enc_w1 = (const float*)d_in[4];
    const float* enc_b1 = (const float*)d_in[5];
    const float* enc_w2 = (const float*)d_in[6];
    const float* enc_b2 = (const float*)d_in[7];
    const float* four_w1 = (const float*)d_in[8];
    const float* four_w2 = (const float*)d_in[9];
    const float* time_w = (const float*)d_in[10];
    const float* l1w1 = (const float*)d_in[11];
    const float* l1b1 = (const float*)d_in[12];
    const float* l1w2 = (const float*)d_in[13];
    const float* l1b2 = (const float*)d_in[14];
    const float* l2w1 = (const float*)d_in[15];
    const float* l2b1 = (const float*)d_in[16];
    const float* l2w2 = (const float*)d_in[17];
    const float* l2b2 = (const float*)d_in[18];
    const float* qkv_w = (const float*)d_in[19];
    const float* qkv_b = (const float*)d_in[20];
    const float* out_w = (const float*)d_in[21];
    const float* out_b = (const float*)d_in[22];
    const float* ln1g = (const float*)d_in[23];
    const float* ln1b = (const float*)d_in[24];
    const float* ff1w = (const float*)d_in[25];
    const float* ff1b = (const float*)d_in[26];
    const float* ff2w = (const float*)d_in[27];
    const float* ff2b = (const float*)d_in[28];
    const float* gam  = (const float*)d_in[29];
    const float* ln2g = (const float*)d_in[30];
    const float* ln2b = (const float*)d_in[31];
    float* out = (float*)d_out;

    float *x, *skip, *big, *dm, *u, *r, *pqbias;
    int* idx;
    us *bigb, *xb, *attb, *lf1b, *pq, *h2b, *feat16, *wt;
    hipGetSymbolAddress((void**)&x,    HIP_SYMBOL(g_x));
    hipGetSymbolAddress((void**)&skip, HIP_SYMBOL(g_skip));
    hipGetSymbolAddress((void**)&big,  HIP_SYMBOL(g_big));
    hipGetSymbolAddress((void**)&dm,   HIP_SYMBOL(g_dm));
    hipGetSymbolAddress((void**)&u,    HIP_SYMBOL(g_u));
    hipGetSymbolAddress((void**)&r,    HIP_SYMBOL(g_r));
    hipGetSymbolAddress((void**)&pqbias, HIP_SYMBOL(g_pqbias));
    hipGetSymbolAddress((void**)&idx,  HIP_SYMBOL(g_idx));
    hipGetSymbolAddress((void**)&bigb, HIP_SYMBOL(g_bigb));
    hipGetSymbolAddress((void**)&xb,   HIP_SYMBOL(g_xb));
    hipGetSymbolAddress((void**)&attb, HIP_SYMBOL(g_attb));
    hipGetSymbolAddress((void**)&lf1b, HIP_SYMBOL(g_lf1b));
    hipGetSymbolAddress((void**)&pq,   HIP_SYMBOL(g_pq));
    hipGetSymbolAddress((void**)&h2b,  HIP_SYMBOL(g_h2b));
    hipGetSymbolAddress((void**)&feat16, HIP_SYMBOL(g_feat16));
    hipGetSymbolAddress((void**)&wt,   HIP_SYMBOL(g_wt));

    // ---- all prep + time + topk2 in one dispatch (8x-batched tiles) ----
    k_uprep<<<UPN, 256, 0, stream>>>(
        enc_w1, enc_w2, l1w2, l2w2, qkv_w, out_w, ff1w, ff2w,
        l1w1, l1b1, l2w1, l2b1, f_feat, f_time, four_w1, four_w2, time_w,
        f_pts, f_mask, wt, pqbias, feat16, u, idx);

    // ---- encoder ----
    k_mg2<1, true><<<dim3(4, 128), 256, 0, stream>>>(feat16, wt + OFF_ENC1, enc_b1, bigb, 32, 512);
    k_mg2<1, false><<<dim3(2, 128), 256, 0, stream>>>(bigb, wt + OFF_ENC2, enc_b2, x, 512, 256);
    // ---- knn pass 1 ----
    k_mg2<0, true><<<dim3(8, 128), 256, 0, stream>>>(feat16, wt + OFF_PQ1, pqbias, pq, 32, 1024);
    k_knng<<<Rn / 128, 512, 0, stream>>>(pq, idx, wt + OFF_W2A, l1b2, h2b);
    k_mean1s<<<Tn, 64, 0, stream>>>(h2b, f_mask, lf1b, big, r);
    // ---- knn pass 2 ----
    k_dist<<<dim3(2, 2, Bn), 256, 0, stream>>>(big, r, dm);
    k_topkg<<<Bn, Nn, 0, stream>>>(dm, idx);
    k_mg2<0, true><<<dim3(8, 128), 256, 0, stream>>>(lf1b, wt + OFF_PQ2, pqbias + 1024, pq, 256, 1024);
    k_knng<<<Rn / 128, 512, 0, stream>>>(pq, idx, wt + OFF_W2B, l2b2, h2b);
    // ---- mean + combine ----
    k_meanc<<<Tn, 256, 0, stream>>>(h2b, u, f_mask, x, skip, xb);
    // ---- transformer layers: qattn -> k_ffn (out+LN1+ff1+ff2+LN2) ----
    for (int l = 0; l < Ln; l++) {
        k_qattn<<<Bn * 8, 256, 0, stream>>>(
            xb, wt + OFF_QKV + (size_t)l * 768 * 256, qkv_b + l * 768, f_mask, attb);
        if (l < Ln - 1)
            k_ffn<false><<<512, 512, 0, stream>>>(
                attb, wt + OFF_OUT + (size_t)l * 256 * 256, out_b + l * 256,
                xb, ln1g + l * Dn, ln1b + l * Dn,
                wt + OFF_FF1 + (size_t)l * 512 * 256, ff1b + l * 512,
                wt + OFF_FF2 + (size_t)l * 256 * 512, ff2b + l * 256,
                gam + l * Dn, f_mask, ln2g + l * Dn, ln2b + l * Dn,
                nullptr, xb, nullptr);
        else
            k_ffn<true><<<512, 512, 0, stream>>>(
                attb, wt + OFF_OUT + (size_t)l * 256 * 256, out_b + l * 256,
                xb, ln1g + l * Dn, ln1b + l * Dn,
                wt + OFF_FF1 + (size_t)l * 512 * 256, ff1b + l * 512,
                wt + OFF_FF2 + (size_t)l * 256 * 512, ff2b + l * 256,
                gam + l * Dn, f_mask, ln2g + l * Dn, ln2b + l * Dn,
                skip, nullptr, out);
    }
}

// Round 13
// 1295.239 us; speedup vs baseline: 1.0428x; 1.0428x over previous
//
#include <hip/hip_runtime.h>
#include <hip/hip_bf16.h>
#include <cmath>

#define DEV_INLINE __device__ __forceinline__

constexpr int Bn = 128;
constexpr int Nn = 128;
constexpr int Fn = 13;
constexpr int Dn = 256;
constexpr int Ln = 8;
constexpr int Kn = 10;
constexpr int FFn = 512;
constexpr int Tn = Bn * Nn;   // 16384
constexpr int Rn = Tn * Kn;   // 163840

typedef __attribute__((ext_vector_type(4))) float f32x4;
typedef __attribute__((ext_vector_type(8))) short bf16x8;
typedef unsigned short us;

// ---------------- static device workspace ----------------
__device__ float g_x[Tn * Dn];
__device__ float g_skip[Tn * Dn];
__device__ float g_big[Tn * Dn];
__device__ float g_dm[Tn * Nn];
__device__ float g_u[Bn * FFn];
__device__ float g_r[Tn];
__device__ float g_pqbias[2048];
__device__ int   g_idx[Rn];
__device__ us g_bigb[Tn * 768];
__device__ us g_xb[Tn * Dn];
__device__ us g_attb[Tn * Dn];
__device__ us g_lf1b[Tn * Dn];
__device__ us g_pq[Tn * 1024];
__device__ us g_h2b[Rn * Dn];
__device__ us g_feat16[Tn * 32];
constexpr int OFF_ENC1 = 0;
constexpr int OFF_ENC2 = OFF_ENC1 + 512 * 32;
constexpr int OFF_W2A  = OFF_ENC2 + 256 * 512;
constexpr int OFF_W2B  = OFF_W2A + 256 * 512;
constexpr int OFF_PQ1  = OFF_W2B + 256 * 512;
constexpr int OFF_PQ2  = OFF_PQ1 + 1024 * 32;
constexpr int OFF_QKV  = OFF_PQ2 + 1024 * 256;
constexpr int OFF_OUT  = OFF_QKV + 8 * 768 * 256;
constexpr int OFF_FF1  = OFF_OUT + 8 * 256 * 256;
constexpr int OFF_FF2  = OFF_FF1 + 8 * 512 * 256;
constexpr int WT_TOTAL = OFF_FF2 + 8 * 256 * 512;
__device__ us g_wt[WT_TOTAL];

// fast gelu: 0.5x(1+tanh(u)) == x / (1 + exp(-2u))
DEV_INLINE float gelu_f(float x) {
    float x2 = x * x;
    float m = x * fmaf(x2, -0.07135537f, -1.59576912f); // -2u
    float t = __expf(m);
    return x * __builtin_amdgcn_rcpf(1.f + t);
}
DEV_INLINE us f2b(float x) {
    __hip_bfloat16 h = __float2bfloat16(x);
    return *(us*)&h;
}
DEV_INLINE float blo(unsigned u) { return __uint_as_float(u << 16); }
DEV_INLINE float bhi(unsigned u) { return __uint_as_float(u & 0xFFFF0000u); }
DEV_INLINE unsigned pk2(float a, float b) {
    float2 f; f.x = a; f.y = b;
    __hip_bfloat162 h = __float22bfloat162_rn(f);
    return *(unsigned*)&h;
}

#define GLOAD16(gp, lp)                                                            \
    __builtin_amdgcn_global_load_lds(                                              \
        (const __attribute__((address_space(1))) unsigned int*)(gp),               \
        (__attribute__((address_space(3))) unsigned int*)(lp), 16, 0, 0)

// =================== über-prep (8x-batched tiles) ===================
constexpr int U0 = 0;
constexpr int U1 = U0 + 2;
constexpr int U2 = U1 + 16;
constexpr int U3 = U2 + 16;
constexpr int U4 = U3 + 16;
constexpr int U5 = U4 + 192;
constexpr int U6 = U5 + 64;
constexpr int U7 = U6 + 128;
constexpr int U8 = U7 + 128;
constexpr int U9 = U8 + 128;
constexpr int U10 = U9 + 128;
constexpr int U11 = U10 + 256;
constexpr int U12 = U11 + 128;
constexpr int UPN = U12 + 128;

DEV_INLINE void prep_seg(const float* __restrict__ src, us* __restrict__ dst,
                         int Kreal, int Kpad, int Nd, long sstride, long dstride,
                         int gx, int gy, int lb, int tid, float* tile) {
    int z = lb / (gx * gy);
    int rem = lb - z * gx * gy;
    int by = rem / gx, bx = rem - by * gx;
    const float* s = src + (size_t)z * sstride;
    us* d = dst + (size_t)z * dstride;
    int cn = tid & 31, rk = tid >> 5;
    int kbase = by * 32, nbase = bx * 32;
#pragma unroll
    for (int p = 0; p < 4; p++) {
        int k = kbase + p * 8 + rk;
        float v = (k < Kreal) ? s[(size_t)k * Nd + nbase + cn] : 0.f;
        tile[(p * 8 + rk) * 33 + cn] = v;
    }
    __syncthreads();
#pragma unroll
    for (int p = 0; p < 4; p++) {
        int nl = p * 8 + rk;
        d[(size_t)(nbase + nl) * Kpad + kbase + cn] = f2b(tile[cn * 33 + nl]);
    }
    __syncthreads();
}

DEV_INLINE void prepPQ_seg(const float* __restrict__ w1, const float* __restrict__ b1,
                           us* __restrict__ dst, float* __restrict__ bdst,
                           int Kreal, int Kpad, int n, int tid) {
    for (int k = tid; k < Kpad; k += 256) {
        float v;
        if (n < 512) v = (k < Kreal) ? w1[(size_t)k * 512 + n] : 0.f;
        else {
            int m = n - 512;
            v = (k < Kreal) ? (w1[(size_t)(Kreal + k) * 512 + m] - w1[(size_t)k * 512 + m]) : 0.f;
        }
        dst[(size_t)n * Kpad + k] = f2b(v);
    }
    if (tid == 0) bdst[n] = (n < 512) ? 0.f : b1[n - 512];
}

__global__ __launch_bounds__(256) void k_uprep(
    const float* __restrict__ enc_w1, const float* __restrict__ enc_w2,
    const float* __restrict__ l1w2, const float* __restrict__ l2w2,
    const float* __restrict__ qkv_w, const float* __restrict__ out_w,
    const float* __restrict__ ff1w, const float* __restrict__ ff2w,
    const float* __restrict__ l1w1, const float* __restrict__ l1b1,
    const float* __restrict__ l2w1, const float* __restrict__ l2b1,
    const float* __restrict__ feat, const float* __restrict__ tin,
    const float* __restrict__ four_w1, const float* __restrict__ four_w2,
    const float* __restrict__ time_w, const float* __restrict__ pts,
    const float* __restrict__ mask,
    us* __restrict__ wt, float* __restrict__ pqbias, us* __restrict__ fp,
    float* __restrict__ u, int* __restrict__ idx) {
    __shared__ float shmem[1056];
    int b = blockIdx.x, tid = threadIdx.x;
    if (b < U1) {
#pragma unroll 1
        for (int i = 0; i < 8; i++)
            prep_seg(enc_w1, wt + OFF_ENC1, 13, 32, 512, 0, 0, 16, 1, (b - U0) * 8 + i, tid, shmem);
    } else if (b < U2) {
#pragma unroll 1
        for (int i = 0; i < 8; i++)
            prep_seg(enc_w2, wt + OFF_ENC2, 512, 512, 256, 0, 0, 8, 16, (b - U1) * 8 + i, tid, shmem);
    } else if (b < U3) {
#pragma unroll 1
        for (int i = 0; i < 8; i++)
            prep_seg(l1w2, wt + OFF_W2A, 512, 512, 256, 0, 0, 8, 16, (b - U2) * 8 + i, tid, shmem);
    } else if (b < U4) {
#pragma unroll 1
        for (int i = 0; i < 8; i++)
            prep_seg(l2w2, wt + OFF_W2B, 512, 512, 256, 0, 0, 8, 16, (b - U3) * 8 + i, tid, shmem);
    } else if (b < U5) {
#pragma unroll 1
        for (int i = 0; i < 8; i++)
            prep_seg(qkv_w, wt + OFF_QKV, 256, 256, 768, 256 * 768, 768 * 256, 24, 8, (b - U4) * 8 + i, tid, shmem);
    } else if (b < U6) {
#pragma unroll 1
        for (int i = 0; i < 8; i++)
            prep_seg(out_w, wt + OFF_OUT, 256, 256, 256, 256 * 256, 256 * 256, 8, 8, (b - U5) * 8 + i, tid, shmem);
    } else if (b < U7) {
#pragma unroll 1
        for (int i = 0; i < 8; i++)
            prep_seg(ff1w, wt + OFF_FF1, 256, 256, 512, 256 * 512, 512 * 256, 16, 8, (b - U6) * 8 + i, tid, shmem);
    } else if (b < U8) {
#pragma unroll 1
        for (int i = 0; i < 8; i++)
            prep_seg(ff2w, wt + OFF_FF2, 512, 512, 256, 512 * 256, 256 * 512, 8, 16, (b - U7) * 8 + i, tid, shmem);
    } else if (b < U9) {
#pragma unroll 1
        for (int i = 0; i < 8; i++)
            prepPQ_seg(l1w1, l1b1, wt + OFF_PQ1, pqbias, 13, 32, (b - U8) * 8 + i, tid);
    } else if (b < U10) {
#pragma unroll 1
        for (int i = 0; i < 8; i++)
            prepPQ_seg(l2w1, l2b1, wt + OFF_PQ2, pqbias + 1024, 256, 256, (b - U9) * 8 + i, tid);
    } else if (b < U11) {
#pragma unroll 1
        for (int i = 0; i < 8; i++) {
            int gid = ((b - U10) * 8 + i) * 256 + tid;
            int t = gid >> 5, c = gid & 31;
            fp[gid] = (c < Fn) ? f2b(feat[(size_t)t * Fn + c]) : (us)0;
        }
    } else if (b < U12) {
        float* e = shmem; float* e1 = shmem + 256; float* t2 = shmem + 768;
        int bb = b - U11;
        float tv = tin[bb];
        if (tid < 128) {
            const float emb = 0.07252236513366287f;
            float fr = expf(-emb * (float)tid);
            float ang = tv * fr * 1000.f;
            e[tid] = sinf(ang);
            e[tid + 128] = cosf(ang);
        }
        __syncthreads();
        for (int j = tid; j < 512; j += 256) {
            float s = 0.f;
            for (int i = 0; i < 256; i++) s += e[i] * four_w1[(size_t)i * 512 + j];
            e1[j] = s / (1.f + expf(-s));
        }
        __syncthreads();
        {
            float s = 0.f;
            for (int i = 0; i < 512; i++) s += e1[i] * four_w2[(size_t)i * 256 + tid];
            t2[tid] = s / (1.f + expf(-s));
        }
        __syncthreads();
        for (int j = tid; j < 512; j += 256) {
            float s = 0.f;
            for (int i = 0; i < 256; i++) s += t2[i] * time_w[(size_t)i * 512 + j];
            u[(size_t)bb * 512 + j] = s;
        }
    } else {
        float* px = shmem; float* py = shmem + 128; float* rr = shmem + 256;
        int bb = b - U12;
        if (tid < 128) {
            int n = tid;
            float shift = 999.f * (1.f - mask[bb * Nn + n]);
            float x = pts[(size_t)(bb * Nn + n) * 2 + 0] + shift;
            float y = pts[(size_t)(bb * Nn + n) * 2 + 1] + shift;
            px[n] = x; py[n] = y; rr[n] = x * x + y * y;
        }
        __syncthreads();
        if (tid < 128) {
            int n = tid;
            float x = px[n], y = py[n], rn = rr[n];
            float bd[Kn + 1]; int bi[Kn + 1];
#pragma unroll
            for (int j = 0; j <= Kn; j++) { bd[j] = 3.4e38f; bi[j] = -1; }
            for (int m = 0; m < Nn; m++) {
                float d = rn - 2.f * (x * px[m] + y * py[m]) + rr[m];
                if (d < bd[Kn]) {
                    int j = Kn;
                    while (j > 0 && d < bd[j - 1]) { bd[j] = bd[j - 1]; bi[j] = bi[j - 1]; j--; }
                    bd[j] = d; bi[j] = m;
                }
            }
            for (int j = 1; j <= Kn; j++) idx[(size_t)(bb * Nn + n) * Kn + j - 1] = bi[j];
        }
    }
}

// ---------------- MFMA GEMM: C = epi(A @ Bt^T + bias), 128x128 tile, XOR bank swizzle ----------------
template <int EPI, bool OBF>
__global__ __launch_bounds__(256) void k_mg2(const us* __restrict__ A,
                                             const us* __restrict__ Bt,
                                             const float* __restrict__ bias,
                                             void* __restrict__ Cp,
                                             int Kd, int Nd) {
    __shared__ __align__(16) us As[128 * 32];
    __shared__ __align__(16) us Bs[128 * 32];
    int tid = threadIdx.x;
    int m0 = blockIdx.y << 7, n0 = blockIdx.x << 7;
    int wave = tid >> 6, lane = tid & 63;
    int wm = (wave & 1) << 6, wn = (wave >> 1) << 6;
    int lm = lane & 15, quad = lane >> 4;
    int r0 = (wave << 5) + (lane >> 2);
    int colu = (((lane & 3) ^ ((lane >> 2) & 3)) << 3);
    const us* pa0 = A + (size_t)(m0 + r0) * Kd + colu;
    const us* pa1 = A + (size_t)(m0 + r0 + 16) * Kd + colu;
    const us* pb0 = Bt + (size_t)(n0 + r0) * Kd + colu;
    const us* pb1 = Bt + (size_t)(n0 + r0 + 16) * Kd + colu;
    auto lAs = (__attribute__((address_space(3))) us*)As;
    auto lBs = (__attribute__((address_space(3))) us*)Bs;
    int lbase = wave << 10;
    int fcol = ((quad ^ (lm & 3)) << 3);
    f32x4 acc[4][4] = {};
    for (int k0 = 0; k0 < Kd; k0 += 32) {
        __syncthreads();
        GLOAD16(pa0 + k0, lAs + lbase);
        GLOAD16(pa1 + k0, lAs + lbase + 512);
        GLOAD16(pb0 + k0, lBs + lbase);
        GLOAD16(pb1 + k0, lBs + lbase + 512);
        __syncthreads();
        bf16x8 afr[4], bfr[4];
#pragma unroll
        for (int i = 0; i < 4; i++) {
            afr[i] = *(const bf16x8*)&As[(wm + i * 16 + lm) * 32 + fcol];
            bfr[i] = *(const bf16x8*)&Bs[(wn + i * 16 + lm) * 32 + fcol];
        }
#pragma unroll
        for (int mf = 0; mf < 4; mf++)
#pragma unroll
            for (int nf = 0; nf < 4; nf++)
                acc[mf][nf] = __builtin_amdgcn_mfma_f32_16x16x32_bf16(afr[mf], bfr[nf], acc[mf][nf], 0, 0, 0);
    }
    float bvs[4];
#pragma unroll
    for (int nf = 0; nf < 4; nf++) bvs[nf] = bias[n0 + wn + nf * 16 + lm];
#pragma unroll
    for (int mf = 0; mf < 4; mf++) {
#pragma unroll
        for (int r = 0; r < 4; r++) {
            size_t row = (size_t)(m0 + wm + mf * 16 + (quad << 2) + r);
#pragma unroll
            for (int nf = 0; nf < 4; nf++) {
                float v = acc[mf][nf][r] + bvs[nf];
                if (EPI == 1) v = gelu_f(v);
                size_t ci = row * Nd + n0 + wn + nf * 16 + lm;
                if constexpr (OBF) ((us*)Cp)[ci] = f2b(v);
                else ((float*)Cp)[ci] = v;
            }
        }
    }
}

// ---------------- fused qkv GEMM + attention: block per (b,h), 256 threads ----------------
__global__ __launch_bounds__(256) void k_qattn(const us* __restrict__ xb,
                                               const us* __restrict__ Bt,
                                               const float* __restrict__ bias,
                                               const float* __restrict__ mask,
                                               us* __restrict__ attb) {
    __shared__ __align__(16) char smem[64512];
    us* Ps = (us*)smem;
    us* Qs = (us*)(smem + 34816);
    us* Ks = (us*)(smem + 45056);
    us* Vt = (us*)(smem + 55296);
    float* msk = (float*)(smem + 64000);
    us* As = (us*)smem;
    us* Bs = (us*)(smem + 8192);
    int bh = blockIdx.x;
    int b = bh >> 3, h = bh & 7;
    int tid = threadIdx.x;
    int wave = tid >> 6, lane = tid & 63;
    int lm = lane & 15, quad = lane >> 4;
    int wm = wave << 5;
    int colu = (((lane & 3) ^ ((lane >> 2) & 3)) << 3);
    int r0 = (wave << 5) + (lane >> 2);
    const us* pa0 = xb + (size_t)(b * 128 + r0) * 256 + colu;
    const us* pa1 = xb + (size_t)(b * 128 + r0 + 16) * 256 + colu;
    int seg0 = wave, seg1 = wave + 4;
    int n0_ = seg0 * 16 + (lane >> 2);
    int n1_ = seg1 * 16 + (lane >> 2);
    int g0 = (n0_ >> 5) * 256 + h * 32 + (n0_ & 31);
    int g1 = (n1_ >> 5) * 256 + h * 32 + (n1_ & 31);
    const us* pb0 = Bt + (size_t)g0 * 256 + colu;
    const us* pb1 = Bt + (size_t)g1 * 256 + colu;
    auto lAs = (__attribute__((address_space(3))) us*)As;
    auto lBs = (__attribute__((address_space(3))) us*)Bs;
    int fcol = ((quad ^ (lm & 3)) << 3);
    f32x4 gacc[2][6] = {};
    for (int k0 = 0; k0 < 256; k0 += 32) {
        __syncthreads();
        GLOAD16(pa0 + k0, lAs + (wave << 10));
        GLOAD16(pa1 + k0, lAs + (wave << 10) + 512);
        GLOAD16(pb0 + k0, lBs + (seg0 << 9));
        if (wave < 2) GLOAD16(pb1 + k0, lBs + (seg1 << 9));
        __syncthreads();
        bf16x8 afr[2], bfr[6];
#pragma unroll
        for (int mf = 0; mf < 2; mf++)
            afr[mf] = *(const bf16x8*)&As[(wm + mf * 16 + lm) * 32 + fcol];
#pragma unroll
        for (int nf = 0; nf < 6; nf++)
            bfr[nf] = *(const bf16x8*)&Bs[(nf * 16 + lm) * 32 + fcol];
#pragma unroll
        for (int mf = 0; mf < 2; mf++)
#pragma unroll
            for (int nf = 0; nf < 6; nf++)
                gacc[mf][nf] = __builtin_amdgcn_mfma_f32_16x16x32_bf16(afr[mf], bfr[nf], gacc[mf][nf], 0, 0, 0);
    }
    float bvq[6];
#pragma unroll
    for (int nf = 0; nf < 6; nf++) {
        int n = nf * 16 + lm;
        bvq[nf] = bias[(n >> 5) * 256 + h * 32 + (n & 31)];
    }
    __syncthreads();
#pragma unroll
    for (int mf = 0; mf < 2; mf++) {
#pragma unroll
        for (int r = 0; r < 4; r++) {
            int row = wm + mf * 16 + (quad << 2) + r;
#pragma unroll
            for (int nf = 0; nf < 6; nf++) {
                us hv = f2b(gacc[mf][nf][r] + bvq[nf]);
                int n = nf * 16 + lm;
                if (nf < 2) Qs[row * 40 + n] = hv;
                else if (nf < 4) Ks[row * 40 + (n - 32)] = hv;
                else Vt[(n - 64) * 136 + row] = hv;
            }
        }
    }
    if (tid < 128) msk[tid] = mask[b * 128 + tid];
    __syncthreads();
    f32x4 acc[2][8] = {};
    {
        bf16x8 aq[2];
#pragma unroll
        for (int mf = 0; mf < 2; mf++)
            aq[mf] = *(const bf16x8*)&Qs[(wm + mf * 16 + lm) * 40 + (quad << 3)];
#pragma unroll
        for (int nf = 0; nf < 8; nf++) {
            bf16x8 bk = *(const bf16x8*)&Ks[(nf * 16 + lm) * 40 + (quad << 3)];
            acc[0][nf] = __builtin_amdgcn_mfma_f32_16x16x32_bf16(aq[0], bk, acc[0][nf], 0, 0, 0);
            acc[1][nf] = __builtin_amdgcn_mfma_f32_16x16x32_bf16(aq[1], bk, acc[1][nf], 0, 0, 0);
        }
    }
    {
        const float sc = 0.17677669529663687f;
        float mkc[8];
#pragma unroll
        for (int nf = 0; nf < 8; nf++) mkc[nf] = msk[nf * 16 + lm];
#pragma unroll
        for (int mf = 0; mf < 2; mf++) {
#pragma unroll
            for (int nf = 0; nf < 8; nf++)
#pragma unroll
                for (int r = 0; r < 4; r++) {
                    float s = acc[mf][nf][r];
                    acc[mf][nf][r] = mkc[nf] > 0.f ? s * sc : -1.0e9f;
                }
#pragma unroll
            for (int r = 0; r < 4; r++) {
                float m = acc[mf][0][r];
#pragma unroll
                for (int nf = 1; nf < 8; nf++) m = fmaxf(m, acc[mf][nf][r]);
                m = fmaxf(m, __shfl_xor(m, 1, 64));
                m = fmaxf(m, __shfl_xor(m, 2, 64));
                m = fmaxf(m, __shfl_xor(m, 4, 64));
                m = fmaxf(m, __shfl_xor(m, 8, 64));
                float s = 0.f;
#pragma unroll
                for (int nf = 0; nf < 8; nf++) {
                    float p = __expf(acc[mf][nf][r] - m);
                    acc[mf][nf][r] = p;
                    s += p;
                }
                s += __shfl_xor(s, 1, 64);
                s += __shfl_xor(s, 2, 64);
                s += __shfl_xor(s, 4, 64);
                s += __shfl_xor(s, 8, 64);
                float linv = __builtin_amdgcn_rcpf(s);
                int prow = wm + mf * 16 + (quad << 2) + r;
#pragma unroll
                for (int nf = 0; nf < 8; nf++)
                    Ps[prow * 136 + nf * 16 + lm] = f2b(acc[mf][nf][r] * linv);
            }
        }
    }
    __syncthreads();
    f32x4 oacc[2][2] = {};
    for (int kt = 0; kt < 4; kt++) {
        bf16x8 ap[2], bv[2];
#pragma unroll
        for (int mf = 0; mf < 2; mf++)
            ap[mf] = *(const bf16x8*)&Ps[(wm + mf * 16 + lm) * 136 + kt * 32 + (quad << 3)];
#pragma unroll
        for (int nf = 0; nf < 2; nf++)
            bv[nf] = *(const bf16x8*)&Vt[(nf * 16 + lm) * 136 + kt * 32 + (quad << 3)];
#pragma unroll
        for (int mf = 0; mf < 2; mf++)
#pragma unroll
            for (int nf = 0; nf < 2; nf++)
                oacc[mf][nf] = __builtin_amdgcn_mfma_f32_16x16x32_bf16(ap[mf], bv[nf], oacc[mf][nf], 0, 0, 0);
    }
#pragma unroll
    for (int mf = 0; mf < 2; mf++)
#pragma unroll
        for (int r = 0; r < 4; r++) {
            int row = wm + mf * 16 + (quad << 2) + r;
#pragma unroll
            for (int nf = 0; nf < 2; nf++)
                attb[(size_t)(b * 128 + row) * 256 + h * 32 + nf * 16 + lm] = f2b(oacc[mf][nf][r]);
        }
}

// ---------------- fused out-proj + LN1 + ff1: 64-row tiles (256 blocks), 512 threads ----------------
__global__ __launch_bounds__(512) void k_mglnff(const us* __restrict__ A,
                                                const us* __restrict__ Bt,
                                                const float* __restrict__ bias,
                                                const us* __restrict__ res,
                                                const float* __restrict__ lng,
                                                const float* __restrict__ lnb,
                                                const us* __restrict__ W1t,
                                                const float* __restrict__ b1,
                                                us* __restrict__ xbout,
                                                us* __restrict__ ffout) {
    __shared__ __align__(16) char smem[57856];
    us* xln = (us*)smem;
    us* As = (us*)(smem + 32768);
    us* Bs = (us*)(smem + 36864);
    us* Bs2 = (us*)(smem + 32768);
    float2* part = (float2*)(smem + 53248);
    float2* stat = (float2*)(smem + 57344);
    int tid = threadIdx.x;
    int m0 = blockIdx.x << 6;
    int wave = tid >> 6, lane = tid & 63;
    int wn = wave << 5;
    int lm = lane & 15, quad = lane >> 4;
    int colu = (((lane & 3) ^ ((lane >> 2) & 3)) << 3);
    int ar = (wave << 4) + (lane >> 2);
    int br = (wave << 5) + (lane >> 2);
    const us* pa = A + (size_t)(m0 + ar) * 256 + colu;
    const us* pb0 = Bt + (size_t)br * 256 + colu;
    const us* pb1 = Bt + (size_t)(br + 16) * 256 + colu;
    auto lAs = (__attribute__((address_space(3))) us*)As;
    auto lBs = (__attribute__((address_space(3))) us*)Bs;
    auto lBs2 = (__attribute__((address_space(3))) us*)Bs2;
    int fcol = ((quad ^ (lm & 3)) << 3);
    f32x4 acc[4][2] = {};
    for (int k0 = 0; k0 < 256; k0 += 32) {
        __syncthreads();
        if (wave < 4) GLOAD16(pa + k0, lAs + (wave << 9));
        GLOAD16(pb0 + k0, lBs + (wave << 10));
        GLOAD16(pb1 + k0, lBs + (wave << 10) + 512);
        __syncthreads();
        bf16x8 afr[4], bfr[2];
#pragma unroll
        for (int i = 0; i < 4; i++)
            afr[i] = *(const bf16x8*)&As[(i * 16 + lm) * 32 + fcol];
#pragma unroll
        for (int j = 0; j < 2; j++)
            bfr[j] = *(const bf16x8*)&Bs[(wn + j * 16 + lm) * 32 + fcol];
#pragma unroll
        for (int mf = 0; mf < 4; mf++)
#pragma unroll
            for (int nf = 0; nf < 2; nf++)
                acc[mf][nf] = __builtin_amdgcn_mfma_f32_16x16x32_bf16(afr[mf], bfr[nf], acc[mf][nf], 0, 0, 0);
    }
    float bvs[2];
#pragma unroll
    for (int nf = 0; nf < 2; nf++) bvs[nf] = bias[wn + nf * 16 + lm];
#pragma unroll
    for (int mf = 0; mf < 4; mf++) {
#pragma unroll
        for (int r = 0; r < 4; r++) {
            int rowl = mf * 16 + (quad << 2) + r;
            size_t row = (size_t)(m0 + rowl);
            float s1 = 0.f, s2 = 0.f;
#pragma unroll
            for (int nf = 0; nf < 2; nf++) {
                int col = wn + nf * 16 + lm;
                float rv = blo((unsigned)res[row * 256 + col]);
                float v = rv + acc[mf][nf][r] + bvs[nf];
                acc[mf][nf][r] = v;
                s1 += v; s2 += v * v;
            }
            s1 += __shfl_xor(s1, 1, 64); s2 += __shfl_xor(s2, 1, 64);
            s1 += __shfl_xor(s1, 2, 64); s2 += __shfl_xor(s2, 2, 64);
            s1 += __shfl_xor(s1, 4, 64); s2 += __shfl_xor(s2, 4, 64);
            s1 += __shfl_xor(s1, 8, 64); s2 += __shfl_xor(s2, 8, 64);
            if (lm == 0) { float2 p; p.x = s1; p.y = s2; part[wave * 64 + rowl] = p; }
        }
    }
    __syncthreads();
    if (tid < 64) {
        float s = 0.f, q = 0.f;
#pragma unroll
        for (int w = 0; w < 8; w++) { float2 p = part[w * 64 + tid]; s += p.x; q += p.y; }
        float mean = s * (1.f / 256.f);
        float var = q * (1.f / 256.f) - mean * mean;
        float2 st; st.x = mean; st.y = rsqrtf(var + 1e-5f);
        stat[tid] = st;
    }
    __syncthreads();
    float gvs[2], bts[2];
#pragma unroll
    for (int nf = 0; nf < 2; nf++) {
        int col = wn + nf * 16 + lm;
        gvs[nf] = lng[col];
        bts[nf] = lnb[col];
    }
#pragma unroll
    for (int mf = 0; mf < 4; mf++) {
#pragma unroll
        for (int r = 0; r < 4; r++) {
            int rowl = mf * 16 + (quad << 2) + r;
            size_t row = (size_t)(m0 + rowl);
            float2 st = stat[rowl];
#pragma unroll
            for (int nf = 0; nf < 2; nf++) {
                int col = wn + nf * 16 + lm;
                float nv = fmaf((acc[mf][nf][r] - st.x) * st.y, gvs[nf], bts[nf]);
                us hv = f2b(nv);
                xbout[row * 256 + col] = hv;
                int phys = (col >> 3) ^ (rowl & 31);
                xln[rowl * 256 + (phys << 3) + (col & 7)] = hv;
            }
        }
    }
    // ---- phase 2: ff1 for these 64 rows, two 256-col halves ----
#pragma unroll 1
    for (int nh = 0; nh < 2; nh++) {
        const us* Bt2 = W1t + (size_t)(nh * 256) * 256;
        const us* qb0 = Bt2 + (size_t)br * 256 + colu;
        const us* qb1 = Bt2 + (size_t)(br + 16) * 256 + colu;
        f32x4 acc2[4][2] = {};
        for (int k0 = 0; k0 < 256; k0 += 32) {
            __syncthreads();
            GLOAD16(qb0 + k0, lBs2 + (wave << 10));
            GLOAD16(qb1 + k0, lBs2 + (wave << 10) + 512);
            __syncthreads();
            bf16x8 afr[4], bfr[2];
#pragma unroll
            for (int i = 0; i < 4; i++) {
                int rowi = i * 16 + lm;
                int lblk = (k0 >> 3) + quad;
                int phys = lblk ^ (rowi & 31);
                afr[i] = *(const bf16x8*)&xln[rowi * 256 + (phys << 3)];
            }
#pragma unroll
            for (int j = 0; j < 2; j++)
                bfr[j] = *(const bf16x8*)&Bs2[(wn + j * 16 + lm) * 32 + fcol];
#pragma unroll
            for (int mf = 0; mf < 4; mf++)
#pragma unroll
                for (int nf = 0; nf < 2; nf++)
                    acc2[mf][nf] = __builtin_amdgcn_mfma_f32_16x16x32_bf16(afr[mf], bfr[nf], acc2[mf][nf], 0, 0, 0);
        }
        float b2v[2];
#pragma unroll
        for (int nf = 0; nf < 2; nf++) b2v[nf] = b1[nh * 256 + wn + nf * 16 + lm];
#pragma unroll
        for (int mf = 0; mf < 4; mf++) {
#pragma unroll
            for (int r = 0; r < 4; r++) {
                size_t row = (size_t)(m0 + mf * 16 + (quad << 2) + r);
#pragma unroll
                for (int nf = 0; nf < 2; nf++) {
                    float v = gelu_f(acc2[mf][nf][r] + b2v[nf]);
                    ffout[row * 512 + nh * 256 + wn + nf * 16 + lm] = f2b(v);
                }
            }
        }
    }
}

// ---------------- fused GEMM + LayerNorm, 64-row tiles (256 blocks), bf16 residual ----------------
template <bool PM, bool FINAL>
__global__ __launch_bounds__(512) void k_mgln(const us* __restrict__ A,
                                              const us* __restrict__ Bt,
                                              const float* __restrict__ bias,
                                              const us* __restrict__ res,
                                              const float* __restrict__ gamma,
                                              const float* __restrict__ mask,
                                              const float* __restrict__ lng,
                                              const float* __restrict__ lnb,
                                              const float* __restrict__ skip,
                                              us* __restrict__ xbout,
                                              float* __restrict__ finout,
                                              int Kd) {
    __shared__ __align__(16) us As[64 * 32];
    __shared__ __align__(16) us Bs[256 * 32];
    __shared__ float2 part[8][64];
    __shared__ float2 stat[64];
    int tid = threadIdx.x;
    int m0 = blockIdx.x << 6;
    int wave = tid >> 6, lane = tid & 63;
    int wn = wave << 5;
    int lm = lane & 15, quad = lane >> 4;
    int colu = (((lane & 3) ^ ((lane >> 2) & 3)) << 3);
    int ar = (wave << 4) + (lane >> 2);
    int br = (wave << 5) + (lane >> 2);
    const us* pa = A + (size_t)(m0 + ar) * Kd + colu;
    const us* pb0 = Bt + (size_t)br * Kd + colu;
    const us* pb1 = Bt + (size_t)(br + 16) * Kd + colu;
    auto lAs = (__attribute__((address_space(3))) us*)As;
    auto lBs = (__attribute__((address_space(3))) us*)Bs;
    int fcol = ((quad ^ (lm & 3)) << 3);
    f32x4 acc[4][2] = {};
    for (int k0 = 0; k0 < Kd; k0 += 32) {
        __syncthreads();
        if (wave < 4) GLOAD16(pa + k0, lAs + (wave << 9));
        GLOAD16(pb0 + k0, lBs + (wave << 10));
        GLOAD16(pb1 + k0, lBs + (wave << 10) + 512);
        __syncthreads();
        bf16x8 afr[4], bfr[2];
#pragma unroll
        for (int i = 0; i < 4; i++)
            afr[i] = *(const bf16x8*)&As[(i * 16 + lm) * 32 + fcol];
#pragma unroll
        for (int j = 0; j < 2; j++)
            bfr[j] = *(const bf16x8*)&Bs[(wn + j * 16 + lm) * 32 + fcol];
#pragma unroll
        for (int mf = 0; mf < 4; mf++)
#pragma unroll
            for (int nf = 0; nf < 2; nf++)
                acc[mf][nf] = __builtin_amdgcn_mfma_f32_16x16x32_bf16(afr[mf], bfr[nf], acc[mf][nf], 0, 0, 0);
    }
    float bvs[2], gms[2];
#pragma unroll
    for (int nf = 0; nf < 2; nf++) {
        int col = wn + nf * 16 + lm;
        bvs[nf] = bias[col];
        if (PM) gms[nf] = gamma[col];
    }
#pragma unroll
    for (int mf = 0; mf < 4; mf++) {
#pragma unroll
        for (int r = 0; r < 4; r++) {
            int rowl = mf * 16 + (quad << 2) + r;
            size_t row = (size_t)(m0 + rowl);
            float mrow = PM ? mask[row] : 0.f;
            float s1 = 0.f, s2 = 0.f;
#pragma unroll
            for (int nf = 0; nf < 2; nf++) {
                int col = wn + nf * 16 + lm;
                float rv = blo((unsigned)res[row * 256 + col]);
                float v = acc[mf][nf][r] + bvs[nf];
                v = PM ? fmaf(v * gms[nf], mrow, rv) : rv + v;
                acc[mf][nf][r] = v;
                s1 += v; s2 += v * v;
            }
            s1 += __shfl_xor(s1, 1, 64); s2 += __shfl_xor(s2, 1, 64);
            s1 += __shfl_xor(s1, 2, 64); s2 += __shfl_xor(s2, 2, 64);
            s1 += __shfl_xor(s1, 4, 64); s2 += __shfl_xor(s2, 4, 64);
            s1 += __shfl_xor(s1, 8, 64); s2 += __shfl_xor(s2, 8, 64);
            if (lm == 0) { float2 p; p.x = s1; p.y = s2; part[wave][rowl] = p; }
        }
    }
    __syncthreads();
    if (tid < 64) {
        float s = 0.f, q = 0.f;
#pragma unroll
        for (int w = 0; w < 8; w++) { float2 p = part[w][tid]; s += p.x; q += p.y; }
        float mean = s * (1.f / 256.f);
        float var = q * (1.f / 256.f) - mean * mean;
        float2 st; st.x = mean; st.y = rsqrtf(var + 1e-5f);
        stat[tid] = st;
    }
    __syncthreads();
    float gvs[2], bts[2];
#pragma unroll
    for (int nf = 0; nf < 2; nf++) {
        int col = wn + nf * 16 + lm;
        gvs[nf] = lng[col];
        bts[nf] = lnb[col];
    }
#pragma unroll
    for (int mf = 0; mf < 4; mf++) {
#pragma unroll
        for (int r = 0; r < 4; r++) {
            int rowl = mf * 16 + (quad << 2) + r;
            size_t row = (size_t)(m0 + rowl);
            float2 st = stat[rowl];
#pragma unroll
            for (int nf = 0; nf < 2; nf++) {
                int col = wn + nf * 16 + lm;
                float nv = fmaf((acc[mf][nf][r] - st.x) * st.y, gvs[nf], bts[nf]);
                if (FINAL) finout[row * 256 + col] = nv + skip[row * 256 + col];
                else xbout[row * 256 + col] = f2b(nv);
            }
        }
    }
}

// ---------------- fused KNN GEMM2, BK=64, XOR swizzle ----------------
__global__ __launch_bounds__(512) void k_knng(const us* __restrict__ pq,
                                              const int* __restrict__ idx,
                                              const us* __restrict__ Bt,
                                              const float* __restrict__ bias,
                                              us* __restrict__ h2b) {
    __shared__ __align__(16) us As[128 * 64];
    __shared__ __align__(16) us Bs[256 * 64];
    int tid = threadIdx.x;
    int m0 = blockIdx.x << 7;
    int wave = tid >> 6, lane = tid & 63;
    int wm = (wave & 1) << 6, wn = (wave >> 1) << 6;
    int lm = lane & 15, quad = lane >> 4;
    int arow = tid >> 2, acolu = (tid & 3) << 4;
    int asw = arow & 7;
    int ablk0 = ((tid & 3) << 1) ^ asw, ablk1 = (((tid & 3) << 1) + 1) ^ asw;
    int r = m0 + arow;
    int tok = r / 10;
    int nb = idx[r];
    int prow = (tok & ~127) + nb;
    const us* Pp = pq + (size_t)prow * 1024 + acolu;
    const us* Qp = pq + (size_t)tok * 1024 + 512 + acolu;
    int brow = (wave << 5) + (lane >> 3);
    int bcol = (((lane & 7) ^ (lane >> 3)) << 3);
    const us* pb = Bt + (size_t)brow * 512 + bcol;
    auto lBs = (__attribute__((address_space(3))) us*)Bs;
    int lbase = wave << 11;
    int fsw = lm & 7;
    f32x4 acc[4][4] = {};
    for (int k0 = 0; k0 < 512; k0 += 64) {
        uint4 pv0 = *(const uint4*)(Pp + k0);
        uint4 pv1 = *(const uint4*)(Pp + k0 + 8);
        uint4 qv0 = *(const uint4*)(Qp + k0);
        uint4 qv1 = *(const uint4*)(Qp + k0 + 8);
        uint4 h0, h1;
        h0.x = pk2(gelu_f(blo(pv0.x) + blo(qv0.x)), gelu_f(bhi(pv0.x) + bhi(qv0.x)));
        h0.y = pk2(gelu_f(blo(pv0.y) + blo(qv0.y)), gelu_f(bhi(pv0.y) + bhi(qv0.y)));
        h0.z = pk2(gelu_f(blo(pv0.z) + blo(qv0.z)), gelu_f(bhi(pv0.z) + bhi(qv0.z)));
        h0.w = pk2(gelu_f(blo(pv0.w) + blo(qv0.w)), gelu_f(bhi(pv0.w) + bhi(qv0.w)));
        h1.x = pk2(gelu_f(blo(pv1.x) + blo(qv1.x)), gelu_f(bhi(pv1.x) + bhi(qv1.x)));
        h1.y = pk2(gelu_f(blo(pv1.y) + blo(qv1.y)), gelu_f(bhi(pv1.y) + bhi(qv1.y)));
        h1.z = pk2(gelu_f(blo(pv1.z) + blo(qv1.z)), gelu_f(bhi(pv1.z) + bhi(qv1.z)));
        h1.w = pk2(gelu_f(blo(pv1.w) + blo(qv1.w)), gelu_f(bhi(pv1.w) + bhi(qv1.w)));
        __syncthreads();
        GLOAD16(pb + k0, lBs + lbase);
        GLOAD16(pb + k0 + 8 * 512, lBs + lbase + 512);
        GLOAD16(pb + k0 + 16 * 512, lBs + lbase + 1024);
        GLOAD16(pb + k0 + 24 * 512, lBs + lbase + 1536);
        *(uint4*)&As[arow * 64 + (ablk0 << 3)] = h0;
        *(uint4*)&As[arow * 64 + (ablk1 << 3)] = h1;
        __syncthreads();
#pragma unroll
        for (int sub = 0; sub < 2; sub++) {
            int lblk = (sub << 2) + quad;
            int fcol = ((lblk ^ fsw) << 3);
            bf16x8 afr[4], bfr[4];
#pragma unroll
            for (int i = 0; i < 4; i++) {
                afr[i] = *(const bf16x8*)&As[(wm + i * 16 + lm) * 64 + fcol];
                bfr[i] = *(const bf16x8*)&Bs[(wn + i * 16 + lm) * 64 + fcol];
            }
#pragma unroll
            for (int mf = 0; mf < 4; mf++)
#pragma unroll
                for (int nf = 0; nf < 4; nf++)
                    acc[mf][nf] = __builtin_amdgcn_mfma_f32_16x16x32_bf16(afr[mf], bfr[nf], acc[mf][nf], 0, 0, 0);
        }
    }
    float bvs[4];
#pragma unroll
    for (int nf = 0; nf < 4; nf++) bvs[nf] = bias[wn + nf * 16 + lm];
#pragma unroll
    for (int mf = 0; mf < 4; mf++) {
#pragma unroll
        for (int rr = 0; rr < 4; rr++) {
            size_t row = (size_t)(m0 + wm + mf * 16 + (quad << 2) + rr);
#pragma unroll
            for (int nf = 0; nf < 4; nf++) {
                float v = gelu_f(acc[mf][nf][rr] + bvs[nf]);
                h2b[row * 256 + wn + nf * 16 + lm] = f2b(v);
            }
        }
    }
}

// ---------------- pass-1 mean + shift + rownorm ----------------
__global__ __launch_bounds__(64) void k_mean1s(const us* __restrict__ h2b,
                                               const float* __restrict__ mask,
                                               us* __restrict__ lfb,
                                               float* __restrict__ big,
                                               float* __restrict__ r) {
    int t = blockIdx.x, lane = threadIdx.x;
    int c = lane << 2;
    const us* p = h2b + (size_t)t * Kn * 256 + c;
    float s0 = 0.f, s1 = 0.f, s2 = 0.f, s3 = 0.f;
#pragma unroll
    for (int k = 0; k < Kn; k++) {
        uint2 v = *(const uint2*)(p + k * 256);
        s0 += blo(v.x); s1 += bhi(v.x);
        s2 += blo(v.y); s3 += bhi(v.y);
    }
    s0 *= 0.1f; s1 *= 0.1f; s2 *= 0.1f; s3 *= 0.1f;
    uint2 ob; ob.x = pk2(s0, s1); ob.y = pk2(s2, s3);
    *(uint2*)&lfb[(size_t)t * 256 + c] = ob;
    float sh = 999.f * (1.f - mask[t]);
    float4 w; w.x = s0 + sh; w.y = s1 + sh; w.z = s2 + sh; w.w = s3 + sh;
    *(float4*)&big[(size_t)t * 256 + c] = w;
    float sq = w.x * w.x + w.y * w.y + w.z * w.z + w.w * w.w;
#pragma unroll
    for (int off = 32; off; off >>= 1) sq += __shfl_xor(sq, off, 64);
    if (lane == 0) r[t] = sq;
}

// ---------------- pairwise distances (f32, 64x64 tiles) ----------------
__global__ __launch_bounds__(256) void k_dist(const float* __restrict__ fe,
                                              const float* __restrict__ r,
                                              float* __restrict__ Dm) {
    int b = blockIdx.z;
    int m0 = blockIdx.x * 64, n0 = blockIdx.y * 64;
    const float* A = fe + (size_t)b * Nn * Dn;
    __shared__ float As[16][68];
    __shared__ float Bs[16][68];
    int tid = threadIdx.x;
    int tx = tid & 15, ty = tid >> 4;
    int ar = tid >> 2, ac = (tid & 3) << 2;
    float acc[4][4] = {};
    for (int k0 = 0; k0 < Dn; k0 += 16) {
        float4 av = *(const float4*)&A[(size_t)(n0 + ar) * Dn + k0 + ac];
        float4 bv = *(const float4*)&A[(size_t)(m0 + ar) * Dn + k0 + ac];
        __syncthreads();
        As[ac + 0][ar] = av.x; As[ac + 1][ar] = av.y; As[ac + 2][ar] = av.z; As[ac + 3][ar] = av.w;
        Bs[ac + 0][ar] = bv.x; Bs[ac + 1][ar] = bv.y; Bs[ac + 2][ar] = bv.z; Bs[ac + 3][ar] = bv.w;
        __syncthreads();
#pragma unroll
        for (int kk = 0; kk < 16; kk++) {
            float4 a = *(const float4*)&As[kk][ty << 2];
            float4 b2 = *(const float4*)&Bs[kk][tx << 2];
            acc[0][0] += a.x * b2.x; acc[0][1] += a.x * b2.y; acc[0][2] += a.x * b2.z; acc[0][3] += a.x * b2.w;
            acc[1][0] += a.y * b2.x; acc[1][1] += a.y * b2.y; acc[1][2] += a.y * b2.z; acc[1][3] += a.y * b2.w;
            acc[2][0] += a.z * b2.x; acc[2][1] += a.z * b2.y; acc[2][2] += a.z * b2.z; acc[2][3] += a.z * b2.w;
            acc[3][0] += a.w * b2.x; acc[3][1] += a.w * b2.y; acc[3][2] += a.w * b2.z; acc[3][3] += a.w * b2.w;
        }
    }
    float4 rm = *(const float4*)&r[b * Nn + m0 + (tx << 2)];
#pragma unroll
    for (int i = 0; i < 4; i++) {
        int n = n0 + (ty << 2) + i;
        float rn = r[b * Nn + n];
        float4 v;
        v.x = rn - 2.f * acc[i][0] + rm.x;
        v.y = rn - 2.f * acc[i][1] + rm.y;
        v.z = rn - 2.f * acc[i][2] + rm.z;
        v.w = rn - 2.f * acc[i][3] + rm.w;
        *(float4*)&Dm[(size_t)b * Nn * Nn + (size_t)n * Nn + m0 + (tx << 2)] = v;
    }
}

__global__ __launch_bounds__(128) void k_topkg(const float* __restrict__ Dm, int* __restrict__ idx) {
    int b = blockIdx.x, n = threadIdx.x;
    const float* row = Dm + (size_t)b * Nn * Nn + (size_t)n * Nn;
    float bd[Kn + 1]; int bi[Kn + 1];
#pragma unroll
    for (int j = 0; j <= Kn; j++) { bd[j] = 3.4e38f; bi[j] = -1; }
    for (int m = 0; m < Nn; m++) {
        float d = row[m];
        if (d < bd[Kn]) {
            int j = Kn;
            while (j > 0 && d < bd[j - 1]) { bd[j] = bd[j - 1]; bi[j] = bi[j - 1]; j--; }
            bd[j] = d; bi[j] = m;
        }
    }
    for (int j = 1; j <= Kn; j++) idx[(size_t)(b * Nn + n) * Kn + j - 1] = bi[j];
}

// ---------------- pass-2 mean fused with combine (bf16 residual out) ----------------
__global__ __launch_bounds__(256) void k_meanc(const us* __restrict__ h2b,
                                               const float* __restrict__ u,
                                               const float* __restrict__ mask,
                                               const float* __restrict__ x,
                                               float* __restrict__ skip,
                                               us* __restrict__ xb) {
    int t = blockIdx.x, c = threadIdx.x;
    const us* p = h2b + (size_t)t * Kn * 256 + c;
    float s = 0.f;
#pragma unroll
    for (int k = 0; k < Kn; k++) s += blo((unsigned)p[k * 256]);
    s *= 0.1f;
    int b = t >> 7;
    float m = mask[t];
    float xv = x[(size_t)t * Dn + c];
    float sc = u[(size_t)b * 512 + c];
    float sh = u[(size_t)b * 512 + 256 + c];
    float v = xv * (1.f + m * sc) + m * sh + s;
    skip[(size_t)t * Dn + c] = v;
    xb[(size_t)t * Dn + c] = f2b(v);
}

extern "C" void kernel_launch(void* const* d_in, const int* in_sizes, int n_in,
                              void* d_out, int out_size, void* d_ws, size_t ws_size,
                              hipStream_t stream) {
    (void)in_sizes; (void)n_in; (void)out_size; (void)d_ws; (void)ws_size;
    const float* f_feat = (const float*)d_in[0];
    const float* f_pts  = (const float*)d_in[1];
    const float* f_mask = (const float*)d_in[2];
    const float* f_time = (const float*)d_in[3];
    const float* enc_w1 = (const float*)d_in[4];
    const float* enc_b1 = (const float*)d_in[5];
    const float* enc_w2 = (const float*)d_in[6];
    const float* enc_b2 = (const float*)d_in[7];
    const float* four_w1 = (const float*)d_in[8];
    const float* four_w2 = (const float*)d_in[9];
    const float* time_w = (const float*)d_in[10];
    const float* l1w1 = (const float*)d_in[11];
    const float* l1b1 = (const float*)d_in[12];
    const float* l1w2 = (const float*)d_in[13];
    const float* l1b2 = (const float*)d_in[14];
    const float* l2w1 = (const float*)d_in[15];
    const float* l2b1 = (const float*)d_in[16];
    const float* l2w2 = (const float*)d_in[17];
    const float* l2b2 = (const float*)d_in[18];
    const float* qkv_w = (const float*)d_in[19];
    const float* qkv_b = (const float*)d_in[20];
    const float* out_w = (const float*)d_in[21];
    const float* out_b = (const float*)d_in[22];
    const float* ln1g = (const float*)d_in[23];
    const float* ln1b = (const float*)d_in[24];
    const float* ff1w = (const float*)d_in[25];
    const float* ff1b = (const float*)d_in[26];
    const float* ff2w = (const float*)d_in[27];
    const float* ff2b = (const float*)d_in[28];
    const float* gam  = (const float*)d_in[29];
    const float* ln2g = (const float*)d_in[30];
    const float* ln2b = (const float*)d_in[31];
    float* out = (float*)d_out;

    float *x, *skip, *big, *dm, *u, *r, *pqbias;
    int* idx;
    us *bigb, *xb, *attb, *lf1b, *pq, *h2b, *feat16, *wt;
    hipGetSymbolAddress((void**)&x,    HIP_SYMBOL(g_x));
    hipGetSymbolAddress((void**)&skip, HIP_SYMBOL(g_skip));
    hipGetSymbolAddress((void**)&big,  HIP_SYMBOL(g_big));
    hipGetSymbolAddress((void**)&dm,   HIP_SYMBOL(g_dm));
    hipGetSymbolAddress((void**)&u,    HIP_SYMBOL(g_u));
    hipGetSymbolAddress((void**)&r,    HIP_SYMBOL(g_r));
    hipGetSymbolAddress((void**)&pqbias, HIP_SYMBOL(g_pqbias));
    hipGetSymbolAddress((void**)&idx,  HIP_SYMBOL(g_idx));
    hipGetSymbolAddress((void**)&bigb, HIP_SYMBOL(g_bigb));
    hipGetSymbolAddress((void**)&xb,   HIP_SYMBOL(g_xb));
    hipGetSymbolAddress((void**)&attb, HIP_SYMBOL(g_attb));
    hipGetSymbolAddress((void**)&lf1b, HIP_SYMBOL(g_lf1b));
    hipGetSymbolAddress((void**)&pq,   HIP_SYMBOL(g_pq));
    hipGetSymbolAddress((void**)&h2b,  HIP_SYMBOL(g_h2b));
    hipGetSymbolAddress((void**)&feat16, HIP_SYMBOL(g_feat16));
    hipGetSymbolAddress((void**)&wt,   HIP_SYMBOL(g_wt));

    // ---- all prep + time + topk2 in one dispatch (8x-batched tiles) ----
    k_uprep<<<UPN, 256, 0, stream>>>(
        enc_w1, enc_w2, l1w2, l2w2, qkv_w, out_w, ff1w, ff2w,
        l1w1, l1b1, l2w1, l2b1, f_feat, f_time, four_w1, four_w2, time_w,
        f_pts, f_mask, wt, pqbias, feat16, u, idx);

    // ---- encoder ----
    k_mg2<1, true><<<dim3(4, 128), 256, 0, stream>>>(feat16, wt + OFF_ENC1, enc_b1, bigb, 32, 512);
    k_mg2<1, false><<<dim3(2, 128), 256, 0, stream>>>(bigb, wt + OFF_ENC2, enc_b2, x, 512, 256);
    // ---- knn pass 1 ----
    k_mg2<0, true><<<dim3(8, 128), 256, 0, stream>>>(feat16, wt + OFF_PQ1, pqbias, pq, 32, 1024);
    k_knng<<<Rn / 128, 512, 0, stream>>>(pq, idx, wt + OFF_W2A, l1b2, h2b);
    k_mean1s<<<Tn, 64, 0, stream>>>(h2b, f_mask, lf1b, big, r);
    // ---- knn pass 2 ----
    k_dist<<<dim3(2, 2, Bn), 256, 0, stream>>>(big, r, dm);
    k_topkg<<<Bn, Nn, 0, stream>>>(dm, idx);
    k_mg2<0, true><<<dim3(8, 128), 256, 0, stream>>>(lf1b, wt + OFF_PQ2, pqbias + 1024, pq, 256, 1024);
    k_knng<<<Rn / 128, 512, 0, stream>>>(pq, idx, wt + OFF_W2B, l2b2, h2b);
    // ---- mean + combine ----
    k_meanc<<<Tn, 256, 0, stream>>>(h2b, u, f_mask, x, skip, xb);
    // ---- transformer layers: qattn -> mglnff(out+LN1+ff1) -> mgln(ff2+LN2) ----
    for (int l = 0; l < Ln; l++) {
        k_qattn<<<Bn * 8, 256, 0, stream>>>(
            xb, wt + OFF_QKV + (size_t)l * 768 * 256, qkv_b + l * 768, f_mask, attb);
        k_mglnff<<<256, 512, 0, stream>>>(
            attb, wt + OFF_OUT + (size_t)l * 256 * 256, out_b + l * 256,
            xb, ln1g + l * Dn, ln1b + l * Dn,
            wt + OFF_FF1 + (size_t)l * 512 * 256, ff1b + l * 512, xb, bigb);
        if (l < Ln - 1)
            k_mgln<true, false><<<256, 512, 0, stream>>>(
                bigb, wt + OFF_FF2 + (size_t)l * 256 * 512, ff2b + l * 256,
                xb, gam + l * Dn, f_mask, ln2g + l * Dn, ln2b + l * Dn, nullptr, xb, nullptr, 512);
        else
            k_mgln<true, true><<<256, 512, 0, stream>>>(
                bigb, wt + OFF_FF2 + (size_t)l * 256 * 512, ff2b + l * 256,
                xb, gam + l * Dn, f_mask, ln2g + l * Dn, ln2b + l * Dn, skip, nullptr, out, 512);
    }
}